// Round 5
// baseline (4512.794 us; speedup 1.0000x reference)
//
#include <hip/hip_runtime.h>
#include <math.h>

#define NN 50000
#define NE 800000
#define HID 128
#define NNH ((size_t)NN * HID)
#define NPAD 50176

typedef __attribute__((ext_vector_type(8))) short short8;
typedef __attribute__((ext_vector_type(4))) float f32x4;

__device__ __forceinline__ ushort f2bf(float f) {
  unsigned u = __float_as_uint(f);
  unsigned r = (u + 0x7fffu + ((u >> 16) & 1u)) >> 16;
  return (ushort)r;
}
__device__ __forceinline__ float bf2f(ushort h) {
  return __uint_as_float(((unsigned)h) << 16);
}
__device__ __forceinline__ float silu_f(float x) { return x / (1.0f + __expf(-x)); }

// ---------------- utility kernels ----------------
__global__ __launch_bounds__(256) void zero4_kernel(float4* __restrict__ p, int n4)
{
  int i = blockIdx.x * 256 + threadIdx.x;
  if (i < n4) p[i] = make_float4(0.f, 0.f, 0.f, 0.f);
}
__global__ __launch_bounds__(256) void zero_i(int* __restrict__ p, int n)
{
  int i = blockIdx.x * 256 + threadIdx.x;
  if (i < n) p[i] = 0;
}

// ---------------- counting sort of edges by src ----------------
__global__ __launch_bounds__(256) void count_src(const int* __restrict__ src, int* __restrict__ cnt)
{
  int e = blockIdx.x * 256 + threadIdx.x;
  if (e < NE) atomicAdd(&cnt[src[e]], 1);
}

__global__ __launch_bounds__(1024) void scan_excl(const int* __restrict__ cnt, int* __restrict__ base, int n)
{
  __shared__ int ws[16];
  int t = threadIdx.x;
  const int per = (n + 1023) / 1024;
  int s0 = t * per;
  int sum = 0;
  for (int i = 0; i < per; ++i) { int idx = s0 + i; if (idx < n) sum += cnt[idx]; }
  int lane = t & 63, w = t >> 6;
  int v = sum;
  #pragma unroll
  for (int m = 1; m < 64; m <<= 1) { int o = __shfl_up(v, m, 64); if (lane >= m) v += o; }
  if (lane == 63) ws[w] = v;
  __syncthreads();
  if (t == 0) { int a = 0; for (int i = 0; i < 16; ++i) { int x = ws[i]; ws[i] = a; a += x; } }
  __syncthreads();
  int run = ws[w] + v - sum;
  for (int i = 0; i < per; ++i) {
    int idx = s0 + i;
    if (idx < n) { base[idx] = run; run += cnt[idx]; }
  }
}

__global__ __launch_bounds__(256) void place_edges(const int* __restrict__ src, const int* __restrict__ dst,
    const int* __restrict__ base, int* __restrict__ cur,
    int* __restrict__ src_s, int* __restrict__ dst_s, int* __restrict__ perm)
{
  int e = blockIdx.x * 256 + threadIdx.x;
  if (e >= NE) return;
  int s = src[e];
  int p = base[s] + atomicAdd(&cur[s], 1);
  src_s[p] = s; dst_s[p] = dst[e]; perm[p] = e;
}

__global__ __launch_bounds__(256) void permute_ea_bf(const float4* __restrict__ ea,
    const int* __restrict__ perm, ushort* __restrict__ ea_s)
{
  int i = blockIdx.x * 256 + threadIdx.x;
  if (i >= NE * 4) return;
  int e = i >> 2, q = i & 3;
  float4 v = ea[(size_t)perm[e] * 4 + q];
  uint2 p;
  p.x = (uint)f2bf(v.x) | ((uint)f2bf(v.y) << 16);
  p.y = (uint)f2bf(v.z) | ((uint)f2bf(v.w) << 16);
  *(uint2*)&ea_s[(size_t)e * 16 + q * 4] = p;
}

// ---------------- weight conversion ----------------
__global__ __launch_bounds__(256) void cvt4(const float* __restrict__ s0, const float* __restrict__ s1,
    const float* __restrict__ s2, const float* __restrict__ s3, ushort* __restrict__ d)
{
  int i = blockIdx.x * 256 + threadIdx.x;
  if (i >= 65536) return;
  const float* s = (i < 16384) ? s0 : (i < 32768) ? s1 : (i < 49152) ? s2 : s3;
  d[i] = f2bf(s[i & 16383]);
}
__global__ __launch_bounds__(256) void cvt_wab(const float* __restrict__ s, ushort* __restrict__ d)
{
  int i = blockIdx.x * 256 + threadIdx.x;
  if (i >= 131072) return;
  int l = i >> 15, rem = i & 32767;
  int r = rem >> 7, c = rem & 127;
  int srow = r & 127, scol = ((r >> 7) << 7) + c;
  d[l * 104448 + r * 128 + c] = f2bf(s[(size_t)l * 34816 + srow * 272 + scol]);
}
__global__ __launch_bounds__(256) void cvt_w1c(const float* __restrict__ s, ushort* __restrict__ d)
{
  int i = blockIdx.x * 256 + threadIdx.x;
  if (i >= 16384) return;
  int l = i >> 12, rem = i & 4095;
  int r = rem >> 5, c = rem & 31;
  d[l * 104448 + r * 32 + c] = (c < 16) ? f2bf(s[(size_t)l * 34816 + r * 272 + 256 + c]) : (ushort)0;
}
// W2 with k-columns permuted to match permuted S layout: d[m][kk] = s[m][(kk&7)*16 + (kk>>3)]
__global__ __launch_bounds__(256) void cvt_w2p(const float* __restrict__ s, ushort* __restrict__ d)
{
  int i = blockIdx.x * 256 + threadIdx.x;
  if (i >= 65536) return;
  int l = i >> 14, rem = i & 16383;
  int m = rem >> 7, kk = rem & 127;
  int lr = kk >> 3, nt = kk & 7;
  d[l * 104448 + m * 128 + kk] = f2bf(s[(size_t)l * 16384 + m * 128 + nt * 16 + lr]);
}
__global__ __launch_bounds__(256) void cvt_std(const float* __restrict__ s, ushort* __restrict__ d,
    int rows, int cols, int lss)
{
  int i = blockIdx.x * 256 + threadIdx.x;
  int n = 4 * rows * cols;
  if (i >= n) return;
  int rc = rows * cols;
  int l = i / rc, rem = i - l * rc;
  d[l * 104448 + rem] = f2bf(s[(size_t)l * lss + rem]);
}

// ---------------- MFMA GEMM: C = [R +] act(ln?(A @ W^T + bias)) ----------------
template<int KT, bool DOBIAS, bool DOLN, bool DOSILU, bool DORES>
__global__ __launch_bounds__(256) void mgemm(
    const float* __restrict__ A0, const float* __restrict__ A1,
    const ushort* __restrict__ Wbf, const float* __restrict__ bias,
    const float* __restrict__ lng, const float* __restrict__ lnb,
    const float* __restrict__ R, float* __restrict__ C, int n)
{
  constexpr int LDA = (KT == 256) ? 264 : 136;
  __shared__ ushort Al[64][LDA];
  const int tid = threadIdx.x;
  const int n0 = blockIdx.x * 64;

  constexpr int SPR = KT / 4;
  #pragma unroll
  for (int i = 0; i < (64 * KT / 4) / 256; ++i) {
    int s = tid + i * 256;
    int row = s / SPR;
    int c4 = (s % SPR) * 4;
    int gr = n0 + row;
    float4 v = make_float4(0.f, 0.f, 0.f, 0.f);
    if (gr < n) {
      if (KT == 256)
        v = (c4 < 128) ? *(const float4*)(A0 + (size_t)gr * HID + c4)
                       : *(const float4*)(A1 + (size_t)gr * HID + (c4 - 128));
      else
        v = *(const float4*)(A0 + (size_t)gr * HID + c4);
    }
    uint2 p;
    p.x = (uint)f2bf(v.x) | ((uint)f2bf(v.y) << 16);
    p.y = (uint)f2bf(v.z) | ((uint)f2bf(v.w) << 16);
    *(uint2*)&Al[row][c4] = p;
  }
  __syncthreads();

  const int w = tid >> 6, l = tid & 63;
  const int lr = l & 15, lh = l >> 4;

  f32x4 zf = {0.f, 0.f, 0.f, 0.f};
  f32x4 acc[8];
  #pragma unroll
  for (int nt = 0; nt < 8; ++nt) acc[nt] = zf;

  #pragma unroll
  for (int q = 0; q < KT / 32; ++q) {
    short8 af = *(const short8*)&Al[w * 16 + lr][q * 32 + lh * 8];
    #pragma unroll
    for (int nt = 0; nt < 8; ++nt) {
      short8 bf = *(const short8*)(Wbf + (size_t)(nt * 16 + lr) * KT + q * 32 + lh * 8);
      acc[nt] = __builtin_amdgcn_mfma_f32_16x16x32_bf16(af, bf, acc[nt], 0, 0, 0);
    }
  }

  float vb[8], gv[8], bv[8];
  #pragma unroll
  for (int nt = 0; nt < 8; ++nt) {
    int col = nt * 16 + lr;
    vb[nt] = DOBIAS ? bias[col] : 0.f;
    if (DOLN) { gv[nt] = lng[col]; bv[nt] = lnb[col]; }
  }

  #pragma unroll
  for (int r = 0; r < 4; ++r) {
    float vals[8];
    #pragma unroll
    for (int nt = 0; nt < 8; ++nt) vals[nt] = acc[nt][r] + vb[nt];
    if (DOLN) {
      float s1 = 0.f, s2 = 0.f;
      #pragma unroll
      for (int nt = 0; nt < 8; ++nt) { s1 += vals[nt]; s2 += vals[nt] * vals[nt]; }
      #pragma unroll
      for (int m = 1; m < 16; m <<= 1) { s1 += __shfl_xor(s1, m, 64); s2 += __shfl_xor(s2, m, 64); }
      float mu = s1 * (1.0f / 128.0f);
      float var = s2 * (1.0f / 128.0f) - mu * mu;
      float rs = rsqrtf(var + 1e-5f);
      #pragma unroll
      for (int nt = 0; nt < 8; ++nt) vals[nt] = (vals[nt] - mu) * rs * gv[nt] + bv[nt];
    }
    if (DOSILU) {
      #pragma unroll
      for (int nt = 0; nt < 8; ++nt) vals[nt] = silu_f(vals[nt]);
    }
    int row = n0 + w * 16 + lh * 4 + r;
    if (row < n) {
      float* cr = C + (size_t)row * HID;
      #pragma unroll
      for (int nt = 0; nt < 8; ++nt) {
        int col = nt * 16 + lr;
        float o = vals[nt];
        if (DORES) o += R[(size_t)row * HID + col];
        cr[col] = o;
      }
    }
  }
}

// ---------------- fused LN + dual GEMM: hn = LN(h); Pa' = perm(hn@Wa^T + b1); Pb' = perm(hn@Wb^T) ----------------
// Pa/Pb stored permuted: value for col (nt*16+lr) at offset lr*8+nt.
__global__ __launch_bounds__(256) void pab_ln(
    const float* __restrict__ Hraw, const ushort* __restrict__ Wab,
    const float* __restrict__ lg, const float* __restrict__ lbp,
    const float* __restrict__ eb1,
    float* __restrict__ Hn, float* __restrict__ Pa, float* __restrict__ Pb, int n)
{
  __shared__ float Hs[64][132];
  __shared__ ushort Al[64][136];
  const int tid = threadIdx.x;
  const int n0 = blockIdx.x * 64;

  #pragma unroll
  for (int i = 0; i < 8; ++i) {
    int s = tid + i * 256;
    int row = s >> 5, c4 = (s & 31) * 4;
    int gr = n0 + row;
    float4 v = make_float4(0.f, 0.f, 0.f, 0.f);
    if (gr < n) v = *(const float4*)(Hraw + (size_t)gr * HID + c4);
    *(float4*)&Hs[row][c4] = v;
  }
  __syncthreads();

  const int w = tid >> 6, l = tid & 63;
  const int lr = l & 15, lh = l >> 4;

  // --- LayerNorm of row (w*16+lr); this lane covers cols lh*32..lh*32+31 ---
  {
    const int row = w * 16 + lr;
    float s1 = 0.f, s2 = 0.f;
    #pragma unroll
    for (int j = 0; j < 8; ++j) {
      float4 v = *(float4*)&Hs[row][lh * 32 + j * 4];
      s1 += v.x + v.y + v.z + v.w;
      s2 += v.x * v.x + v.y * v.y + v.z * v.z + v.w * v.w;
    }
    s1 += __shfl_xor(s1, 16, 64); s1 += __shfl_xor(s1, 32, 64);
    s2 += __shfl_xor(s2, 16, 64); s2 += __shfl_xor(s2, 32, 64);
    float mu = s1 * (1.0f / 128.0f);
    float var = s2 * (1.0f / 128.0f) - mu * mu;
    float rs = rsqrtf(var + 1e-5f);
    int gr = n0 + row;
    #pragma unroll
    for (int j = 0; j < 8; ++j) {
      int c = lh * 32 + j * 4;
      float4 v = *(float4*)&Hs[row][c];
      float4 o;
      o.x = (v.x - mu) * rs * lg[c + 0] + lbp[c + 0];
      o.y = (v.y - mu) * rs * lg[c + 1] + lbp[c + 1];
      o.z = (v.z - mu) * rs * lg[c + 2] + lbp[c + 2];
      o.w = (v.w - mu) * rs * lg[c + 3] + lbp[c + 3];
      if (gr < n) *(float4*)(Hn + (size_t)gr * HID + c) = o;
      uint2 p;
      p.x = (uint)f2bf(o.x) | ((uint)f2bf(o.y) << 16);
      p.y = (uint)f2bf(o.z) | ((uint)f2bf(o.w) << 16);
      *(uint2*)&Al[row][c] = p;
    }
  }
  __syncthreads();

  f32x4 zf = {0.f, 0.f, 0.f, 0.f};
  f32x4 acc[16];
  #pragma unroll
  for (int nt = 0; nt < 16; ++nt) acc[nt] = zf;

  #pragma unroll
  for (int q = 0; q < 4; ++q) {
    short8 af = *(const short8*)&Al[w * 16 + lr][q * 32 + lh * 8];
    #pragma unroll
    for (int nt = 0; nt < 16; ++nt) {
      short8 bf = *(const short8*)(Wab + (size_t)(nt * 16 + lr) * HID + q * 32 + lh * 8);
      acc[nt] = __builtin_amdgcn_mfma_f32_16x16x32_bf16(af, bf, acc[nt], 0, 0, 0);
    }
  }

  float be[8];
  #pragma unroll
  for (int nt = 0; nt < 8; ++nt) be[nt] = eb1[nt * 16 + lr];

  #pragma unroll
  for (int r = 0; r < 4; ++r) {
    int row = n0 + w * 16 + lh * 4 + r;
    if (row >= n) break;
    float4 a0, a1, b0, b1;
    a0.x = acc[0][r] + be[0]; a0.y = acc[1][r] + be[1]; a0.z = acc[2][r] + be[2]; a0.w = acc[3][r] + be[3];
    a1.x = acc[4][r] + be[4]; a1.y = acc[5][r] + be[5]; a1.z = acc[6][r] + be[6]; a1.w = acc[7][r] + be[7];
    b0.x = acc[8][r];  b0.y = acc[9][r];  b0.z = acc[10][r]; b0.w = acc[11][r];
    b1.x = acc[12][r]; b1.y = acc[13][r]; b1.z = acc[14][r]; b1.w = acc[15][r];
    *(float4*)(Pa + (size_t)row * HID + lr * 8)     = a0;
    *(float4*)(Pa + (size_t)row * HID + lr * 8 + 4) = a1;
    *(float4*)(Pb + (size_t)row * HID + lr * 8)     = b0;
    *(float4*)(Pb + (size_t)row * HID + lr * 8 + 4) = b1;
  }
}

// ---------------- edge kernel (permuted Pa/Pb/S): T = SiLU(LN(Pa'[src]+Pb'[dst]+ea@W1c^T)); S'[src] += T ----------------
__global__ __launch_bounds__(256) void edge_s(
    const float* __restrict__ Pa, const float* __restrict__ Pb,
    const ushort* __restrict__ ea_bf,
    const int* __restrict__ src_s, const int* __restrict__ dst_s,
    const ushort* __restrict__ W1c,
    const float* __restrict__ elg, const float* __restrict__ elb,
    float* __restrict__ S)
{
  const int tid = threadIdx.x;
  const int w = tid >> 6, l = tid & 63;
  const int lr = l & 15, lh = l >> 4;
  const int e0 = blockIdx.x * 64 + w * 16;

  short8 af = {0, 0, 0, 0, 0, 0, 0, 0};
  if (lh < 2) af = *(const short8*)(ea_bf + (size_t)(e0 + lr) * 16 + lh * 8);

  f32x4 zf = {0.f, 0.f, 0.f, 0.f};
  f32x4 acc[8];
  #pragma unroll
  for (int nt = 0; nt < 8; ++nt) acc[nt] = zf;
  #pragma unroll
  for (int nt = 0; nt < 8; ++nt) {
    short8 bf = *(const short8*)(W1c + (nt * 16 + lr) * 32 + lh * 8);
    acc[nt] = __builtin_amdgcn_mfma_f32_16x16x32_bf16(af, bf, acc[nt], 0, 0, 0);
  }

  int sr[4], dr[4];
  #pragma unroll
  for (int r = 0; r < 4; ++r) {
    int e = e0 + lh * 4 + r;
    sr[r] = src_s[e]; dr[r] = dst_s[e];
  }
  int first = __builtin_amdgcn_readfirstlane(sr[0]);
  int last  = __shfl(sr[3], 48, 64);
  bool uni = (first == last);

  // vectorized gathers from permuted layout: lane's 8 values contiguous at lr*8
  if (uni) {
    float4 pa0 = *(const float4*)(Pa + (size_t)first * HID + lr * 8);
    float4 pa1 = *(const float4*)(Pa + (size_t)first * HID + lr * 8 + 4);
    #pragma unroll
    for (int r = 0; r < 4; ++r) {
      float4 pb0 = *(const float4*)(Pb + (size_t)dr[r] * HID + lr * 8);
      float4 pb1 = *(const float4*)(Pb + (size_t)dr[r] * HID + lr * 8 + 4);
      acc[0][r] += pa0.x + pb0.x; acc[1][r] += pa0.y + pb0.y;
      acc[2][r] += pa0.z + pb0.z; acc[3][r] += pa0.w + pb0.w;
      acc[4][r] += pa1.x + pb1.x; acc[5][r] += pa1.y + pb1.y;
      acc[6][r] += pa1.z + pb1.z; acc[7][r] += pa1.w + pb1.w;
    }
  } else {
    #pragma unroll
    for (int r = 0; r < 4; ++r) {
      float4 pa0 = *(const float4*)(Pa + (size_t)sr[r] * HID + lr * 8);
      float4 pa1 = *(const float4*)(Pa + (size_t)sr[r] * HID + lr * 8 + 4);
      float4 pb0 = *(const float4*)(Pb + (size_t)dr[r] * HID + lr * 8);
      float4 pb1 = *(const float4*)(Pb + (size_t)dr[r] * HID + lr * 8 + 4);
      acc[0][r] += pa0.x + pb0.x; acc[1][r] += pa0.y + pb0.y;
      acc[2][r] += pa0.z + pb0.z; acc[3][r] += pa0.w + pb0.w;
      acc[4][r] += pa1.x + pb1.x; acc[5][r] += pa1.y + pb1.y;
      acc[6][r] += pa1.z + pb1.z; acc[7][r] += pa1.w + pb1.w;
    }
  }

  float gv[8], bv[8];
  #pragma unroll
  for (int nt = 0; nt < 8; ++nt) { gv[nt] = elg[nt * 16 + lr]; bv[nt] = elb[nt * 16 + lr]; }

  #pragma unroll
  for (int r = 0; r < 4; ++r) {
    float s1 = 0.f, s2 = 0.f;
    #pragma unroll
    for (int nt = 0; nt < 8; ++nt) { s1 += acc[nt][r]; s2 += acc[nt][r] * acc[nt][r]; }
    #pragma unroll
    for (int m = 1; m < 16; m <<= 1) { s1 += __shfl_xor(s1, m, 64); s2 += __shfl_xor(s2, m, 64); }
    float mu = s1 * (1.0f / 128.0f);
    float var = s2 * (1.0f / 128.0f) - mu * mu;
    float rs = rsqrtf(var + 1e-5f);
    #pragma unroll
    for (int nt = 0; nt < 8; ++nt)
      acc[nt][r] = silu_f((acc[nt][r] - mu) * rs * gv[nt] + bv[nt]);
  }

  #pragma unroll
  for (int nt = 0; nt < 8; ++nt) {
    if (uni) {
      float s = acc[nt][0] + acc[nt][1] + acc[nt][2] + acc[nt][3];
      s += __shfl_xor(s, 16, 64);
      s += __shfl_xor(s, 32, 64);
      if (lh == 0)
        unsafeAtomicAdd(S + (size_t)first * HID + lr * 8 + nt, s);
    } else {
      float run = acc[nt][0];
      #pragma unroll
      for (int r = 1; r < 4; ++r) {
        if (sr[r] == sr[r - 1]) run += acc[nt][r];
        else {
          unsafeAtomicAdd(S + (size_t)sr[r - 1] * HID + lr * 8 + nt, run);
          run = acc[nt][r];
        }
      }
      unsafeAtomicAdd(S + (size_t)sr[3] * HID + lr * 8 + nt, run);
    }
  }
}

// ---------------- agg = (S_hi + S_lo) @ W2'^T + deg*b2 (hi/lo bf16 split; S,W2' permuted k) ----------------
__global__ __launch_bounds__(256) void agg_gemm(
    const float* __restrict__ S, const ushort* __restrict__ W2bf,
    const float* __restrict__ b2, const int* __restrict__ deg,
    float* __restrict__ agg, int n)
{
  __shared__ ushort Ah[64][136];
  __shared__ ushort Alo[64][136];
  const int tid = threadIdx.x;
  const int n0 = blockIdx.x * 64;

  #pragma unroll
  for (int i = 0; i < 8; ++i) {
    int s = tid + i * 256;
    int row = s >> 5;
    int c4 = (s & 31) * 4;
    int gr = n0 + row;
    float4 v = make_float4(0.f, 0.f, 0.f, 0.f);
    if (gr < n) v = *(const float4*)(S + (size_t)gr * HID + c4);
    ushort hx = f2bf(v.x), hy = f2bf(v.y), hz = f2bf(v.z), hw = f2bf(v.w);
    uint2 ph, pl;
    ph.x = (uint)hx | ((uint)hy << 16);
    ph.y = (uint)hz | ((uint)hw << 16);
    pl.x = (uint)f2bf(v.x - bf2f(hx)) | ((uint)f2bf(v.y - bf2f(hy)) << 16);
    pl.y = (uint)f2bf(v.z - bf2f(hz)) | ((uint)f2bf(v.w - bf2f(hw)) << 16);
    *(uint2*)&Ah[row][c4]  = ph;
    *(uint2*)&Alo[row][c4] = pl;
  }
  __syncthreads();

  const int w = tid >> 6, l = tid & 63;
  const int lr = l & 15, lh = l >> 4;

  f32x4 zf = {0.f, 0.f, 0.f, 0.f};
  f32x4 acc[8];
  #pragma unroll
  for (int nt = 0; nt < 8; ++nt) acc[nt] = zf;

  #pragma unroll
  for (int q = 0; q < 4; ++q) {
    short8 ah = *(const short8*)&Ah[w * 16 + lr][q * 32 + lh * 8];
    short8 al = *(const short8*)&Alo[w * 16 + lr][q * 32 + lh * 8];
    #pragma unroll
    for (int nt = 0; nt < 8; ++nt) {
      short8 bf = *(const short8*)(W2bf + (size_t)(nt * 16 + lr) * HID + q * 32 + lh * 8);
      acc[nt] = __builtin_amdgcn_mfma_f32_16x16x32_bf16(ah, bf, acc[nt], 0, 0, 0);
      acc[nt] = __builtin_amdgcn_mfma_f32_16x16x32_bf16(al, bf, acc[nt], 0, 0, 0);
    }
  }

  #pragma unroll
  for (int r = 0; r < 4; ++r) {
    int row = n0 + w * 16 + lh * 4 + r;
    if (row >= n) break;
    float degf = (float)deg[row];
    float* ar = agg + (size_t)row * HID;
    #pragma unroll
    for (int nt = 0; nt < 8; ++nt) {
      int col = nt * 16 + lr;
      ar[col] = acc[nt][r] + degf * b2[col];
    }
  }
}

extern "C" void kernel_launch(void* const* d_in, const int* in_sizes, int n_in,
                              void* d_out, int out_size, void* d_ws, size_t ws_size,
                              hipStream_t stream)
{
  const float* in_h  = (const float*)d_in[0];
  const int*   edges = (const int*)d_in[1];
  const float* ea    = (const float*)d_in[2];
  const float* ei_w1 = (const float*)d_in[3];
  const float* ei_b1 = (const float*)d_in[4];
  const float* ei_w2 = (const float*)d_in[5];
  const float* ei_b2 = (const float*)d_in[6];
  const float* ng    = (const float*)d_in[7];
  const float* nbp   = (const float*)d_in[8];
  const float* ew1   = (const float*)d_in[9];
  const float* eb1   = (const float*)d_in[10];
  const float* elg   = (const float*)d_in[11];
  const float* elb   = (const float*)d_in[12];
  const float* ew2   = (const float*)d_in[13];
  const float* eb2   = (const float*)d_in[14];
  const float* nw1   = (const float*)d_in[15];
  const float* nb1   = (const float*)d_in[16];
  const float* nlg   = (const float*)d_in[17];
  const float* nlb   = (const float*)d_in[18];
  const float* nw2   = (const float*)d_in[19];
  const float* nb2   = (const float*)d_in[20];
  const float* eo_w1 = (const float*)d_in[21];
  const float* eo_b1 = (const float*)d_in[22];
  const float* eo_w2 = (const float*)d_in[23];
  const float* eo_b2 = (const float*)d_in[24];

  float* wf    = (float*)d_ws;
  float* B_h   = wf;
  float* B_hn  = wf + NNH;
  float* B_S   = wf + 2 * NNH;   // S (edge-sum, permuted); perm alias during setup
  float* B_tmp = wf + 3 * NNH;   // Pa' / MLP intermediate
  float* B_pb  = wf + 4 * NNH;   // Pb' during edge phase; agg afterwards

  const size_t WOFF = 5 * NNH;
  ushort* wu = (ushort*)(wf + WOFF);
  // ei1@0, ei2@16384, eo1@32768, eo2@49152; per-layer base 65536 + l*104448:
  //   Wab@0 [256][128] | W2'@32768 | N1@49152 [128][256] | N2@81920 | W1c@98304 [128][32]
  const size_t SOFF = WOFF + 262144;
  int* src_s = (int*)(wf + SOFF);
  int* dst_s = src_s + NE;
  int* cnt   = dst_s + NE;       // = deg
  int* cur   = cnt + NPAD;
  int* base  = cur + NPAD;
  ushort* ea_s = (ushort*)(base + NPAD);
  int* perm  = (int*)B_S;

  const int NB  = (NN + 63) / 64;
  const int EB  = NE / 64;
  const int ZB  = ((int)(NNH / 4) + 255) / 256;
  const int NEB = (NE + 255) / 256;

  const int* erow = edges;
  const int* ecol = edges + NE;

  // ---- counting sort by src (once) ----
  zero_i<<<(2 * NPAD + 255) / 256, 256, 0, stream>>>(cnt, 2 * NPAD);
  count_src<<<NEB, 256, 0, stream>>>(erow, cnt);
  scan_excl<<<1, 1024, 0, stream>>>(cnt, base, NN);
  place_edges<<<NEB, 256, 0, stream>>>(erow, ecol, base, cur, src_s, dst_s, perm);
  permute_ea_bf<<<(NE * 4 + 255) / 256, 256, 0, stream>>>((const float4*)ea, perm, ea_s);

  // ---- weight conversion to bf16 ----
  cvt4<<<256, 256, 0, stream>>>(ei_w1, ei_w2, eo_w1, eo_w2, wu);
  cvt_wab<<<512, 256, 0, stream>>>(ew1, wu + 65536);
  cvt_w1c<<<64, 256, 0, stream>>>(ew1, wu + 65536 + 98304);
  cvt_w2p<<<256, 256, 0, stream>>>(ew2, wu + 65536 + 32768);
  cvt_std<<<(4 * 32768 + 255) / 256, 256, 0, stream>>>(nw1, wu + 65536 + 49152, 128, 256, 32768);
  cvt_std<<<(4 * 16384 + 255) / 256, 256, 0, stream>>>(nw2, wu + 65536 + 81920, 128, 128, 16384);

  // ---- embedding_in ----
  mgemm<128, true, false, true,  false><<<NB, 256, 0, stream>>>(in_h, nullptr, wu, ei_b1, nullptr, nullptr, nullptr, B_tmp, NN);
  mgemm<128, true, false, false, false><<<NB, 256, 0, stream>>>(B_tmp, nullptr, wu + 16384, ei_b2, nullptr, nullptr, nullptr, B_h, NN);

  for (int lyr = 0; lyr < 4; ++lyr) {
    ushort* lb = wu + 65536 + lyr * 104448;
    pab_ln<<<NB, 256, 0, stream>>>(B_h, lb, ng + 128 * lyr, nbp + 128 * lyr,
        eb1 + 128 * lyr, B_hn, B_tmp, B_pb, NN);
    zero4_kernel<<<ZB, 256, 0, stream>>>((float4*)B_S, (int)(NNH / 4));
    edge_s<<<EB, 256, 0, stream>>>(B_tmp, B_pb, ea_s, src_s, dst_s,
        lb + 98304, elg + 128 * lyr, elb + 128 * lyr, B_S);
    agg_gemm<<<NB, 256, 0, stream>>>(B_S, lb + 32768, eb2 + 128 * lyr, cnt, B_pb, NN);
    mgemm<256, true, true,  true,  false><<<NB, 256, 0, stream>>>(B_hn, B_pb, lb + 49152, nb1 + 128 * lyr,
        nlg + 128 * lyr, nlb + 128 * lyr, nullptr, B_tmp, NN);
    mgemm<128, true, false, false, true ><<<NB, 256, 0, stream>>>(B_tmp, nullptr, lb + 81920, nb2 + 128 * lyr,
        nullptr, nullptr, B_hn, B_h, NN);
  }

  // ---- embedding_out ----
  mgemm<128, true, false, true,  false><<<NB, 256, 0, stream>>>(B_h, nullptr, wu + 32768, eo_b1, nullptr, nullptr, nullptr, B_tmp, NN);
  mgemm<128, true, false, false, false><<<NB, 256, 0, stream>>>(B_tmp, nullptr, wu + 49152, eo_b2, nullptr, nullptr, nullptr, (float*)d_out, NN);
}

// Round 6
// 1941.308 us; speedup vs baseline: 2.3246x; 2.3246x over previous
//
#include <hip/hip_runtime.h>
#include <math.h>

#define NN 50000
#define NE 800000
#define HID 128
#define NNH ((size_t)NN * HID)
#define NPAD 50176

typedef __attribute__((ext_vector_type(8))) short short8;
typedef __attribute__((ext_vector_type(4))) float f32x4;

__device__ __forceinline__ ushort f2bf(float f) {
  unsigned u = __float_as_uint(f);
  unsigned r = (u + 0x7fffu + ((u >> 16) & 1u)) >> 16;
  return (ushort)r;
}
__device__ __forceinline__ float bf2f(ushort h) {
  return __uint_as_float(((unsigned)h) << 16);
}
__device__ __forceinline__ float silu_f(float x) { return x / (1.0f + __expf(-x)); }

// ---------------- utility kernels ----------------
__global__ __launch_bounds__(256) void zero4_kernel(float4* __restrict__ p, int n4)
{
  int i = blockIdx.x * 256 + threadIdx.x;
  if (i < n4) p[i] = make_float4(0.f, 0.f, 0.f, 0.f);
}
__global__ __launch_bounds__(256) void zero_i(int* __restrict__ p, int n)
{
  int i = blockIdx.x * 256 + threadIdx.x;
  if (i < n) p[i] = 0;
}

// ---------------- counting sort of edges by src ----------------
__global__ __launch_bounds__(256) void count_src(const int* __restrict__ src, int* __restrict__ cnt)
{
  int e = blockIdx.x * 256 + threadIdx.x;
  if (e < NE) atomicAdd(&cnt[src[e]], 1);
}

__global__ __launch_bounds__(1024) void scan_excl(const int* __restrict__ cnt, int* __restrict__ base, int n)
{
  __shared__ int ws[16];
  int t = threadIdx.x;
  const int per = (n + 1023) / 1024;
  int s0 = t * per;
  int sum = 0;
  for (int i = 0; i < per; ++i) { int idx = s0 + i; if (idx < n) sum += cnt[idx]; }
  int lane = t & 63, w = t >> 6;
  int v = sum;
  #pragma unroll
  for (int m = 1; m < 64; m <<= 1) { int o = __shfl_up(v, m, 64); if (lane >= m) v += o; }
  if (lane == 63) ws[w] = v;
  __syncthreads();
  if (t == 0) { int a = 0; for (int i = 0; i < 16; ++i) { int x = ws[i]; ws[i] = a; a += x; } }
  __syncthreads();
  int run = ws[w] + v - sum;
  for (int i = 0; i < per; ++i) {
    int idx = s0 + i;
    if (idx < n) { base[idx] = run; run += cnt[idx]; }
  }
}

__global__ __launch_bounds__(256) void place_edges(const int* __restrict__ src, const int* __restrict__ dst,
    const int* __restrict__ base, int* __restrict__ cur,
    int* __restrict__ src_s, int* __restrict__ dst_s, int* __restrict__ perm)
{
  int e = blockIdx.x * 256 + threadIdx.x;
  if (e >= NE) return;
  int s = src[e];
  int p = base[s] + atomicAdd(&cur[s], 1);
  src_s[p] = s; dst_s[p] = dst[e]; perm[p] = e;
}

__global__ __launch_bounds__(256) void permute_ea_bf(const float4* __restrict__ ea,
    const int* __restrict__ perm, ushort* __restrict__ ea_s)
{
  int i = blockIdx.x * 256 + threadIdx.x;
  if (i >= NE * 4) return;
  int e = i >> 2, q = i & 3;
  float4 v = ea[(size_t)perm[e] * 4 + q];
  uint2 p;
  p.x = (uint)f2bf(v.x) | ((uint)f2bf(v.y) << 16);
  p.y = (uint)f2bf(v.z) | ((uint)f2bf(v.w) << 16);
  *(uint2*)&ea_s[(size_t)e * 16 + q * 4] = p;
}

// ---------------- weight conversion ----------------
__global__ __launch_bounds__(256) void cvt4(const float* __restrict__ s0, const float* __restrict__ s1,
    const float* __restrict__ s2, const float* __restrict__ s3, ushort* __restrict__ d)
{
  int i = blockIdx.x * 256 + threadIdx.x;
  if (i >= 65536) return;
  const float* s = (i < 16384) ? s0 : (i < 32768) ? s1 : (i < 49152) ? s2 : s3;
  d[i] = f2bf(s[i & 16383]);
}
__global__ __launch_bounds__(256) void cvt_wab(const float* __restrict__ s, ushort* __restrict__ d)
{
  int i = blockIdx.x * 256 + threadIdx.x;
  if (i >= 131072) return;
  int l = i >> 15, rem = i & 32767;
  int r = rem >> 7, c = rem & 127;
  int srow = r & 127, scol = ((r >> 7) << 7) + c;
  d[l * 104448 + r * 128 + c] = f2bf(s[(size_t)l * 34816 + srow * 272 + scol]);
}
__global__ __launch_bounds__(256) void cvt_w1c(const float* __restrict__ s, ushort* __restrict__ d)
{
  int i = blockIdx.x * 256 + threadIdx.x;
  if (i >= 16384) return;
  int l = i >> 12, rem = i & 4095;
  int r = rem >> 5, c = rem & 31;
  d[l * 104448 + r * 32 + c] = (c < 16) ? f2bf(s[(size_t)l * 34816 + r * 272 + 256 + c]) : (ushort)0;
}
__global__ __launch_bounds__(256) void cvt_std(const float* __restrict__ s, ushort* __restrict__ d,
    int rows, int cols, int lss)
{
  int i = blockIdx.x * 256 + threadIdx.x;
  int n = 4 * rows * cols;
  if (i >= n) return;
  int rc = rows * cols;
  int l = i / rc, rem = i - l * rc;
  d[l * 104448 + rem] = f2bf(s[(size_t)l * lss + rem]);
}

// ---------------- MFMA GEMM: C = [R +] act(ln?(A @ W^T + bias)) ----------------
template<int KT, bool DOBIAS, bool DOLN, bool DOSILU, bool DORES>
__global__ __launch_bounds__(256) void mgemm(
    const float* __restrict__ A0, const float* __restrict__ A1,
    const ushort* __restrict__ Wbf, const float* __restrict__ bias,
    const float* __restrict__ lng, const float* __restrict__ lnb,
    const float* __restrict__ R, float* __restrict__ C, int n)
{
  constexpr int LDA = (KT == 256) ? 264 : 136;
  __shared__ ushort Al[64][LDA];
  const int tid = threadIdx.x;
  const int n0 = blockIdx.x * 64;

  constexpr int SPR = KT / 4;
  #pragma unroll
  for (int i = 0; i < (64 * KT / 4) / 256; ++i) {
    int s = tid + i * 256;
    int row = s / SPR;
    int c4 = (s % SPR) * 4;
    int gr = n0 + row;
    float4 v = make_float4(0.f, 0.f, 0.f, 0.f);
    if (gr < n) {
      if (KT == 256)
        v = (c4 < 128) ? *(const float4*)(A0 + (size_t)gr * HID + c4)
                       : *(const float4*)(A1 + (size_t)gr * HID + (c4 - 128));
      else
        v = *(const float4*)(A0 + (size_t)gr * HID + c4);
    }
    uint2 p;
    p.x = (uint)f2bf(v.x) | ((uint)f2bf(v.y) << 16);
    p.y = (uint)f2bf(v.z) | ((uint)f2bf(v.w) << 16);
    *(uint2*)&Al[row][c4] = p;
  }
  __syncthreads();

  const int w = tid >> 6, l = tid & 63;
  const int lr = l & 15, lh = l >> 4;

  f32x4 zf = {0.f, 0.f, 0.f, 0.f};
  f32x4 acc[8];
  #pragma unroll
  for (int nt = 0; nt < 8; ++nt) acc[nt] = zf;

  #pragma unroll
  for (int q = 0; q < KT / 32; ++q) {
    short8 af = *(const short8*)&Al[w * 16 + lr][q * 32 + lh * 8];
    #pragma unroll
    for (int nt = 0; nt < 8; ++nt) {
      short8 bf = *(const short8*)(Wbf + (size_t)(nt * 16 + lr) * KT + q * 32 + lh * 8);
      acc[nt] = __builtin_amdgcn_mfma_f32_16x16x32_bf16(af, bf, acc[nt], 0, 0, 0);
    }
  }

  float vb[8], gv[8], bv[8];
  #pragma unroll
  for (int nt = 0; nt < 8; ++nt) {
    int col = nt * 16 + lr;
    vb[nt] = DOBIAS ? bias[col] : 0.f;
    if (DOLN) { gv[nt] = lng[col]; bv[nt] = lnb[col]; }
  }

  #pragma unroll
  for (int r = 0; r < 4; ++r) {
    float vals[8];
    #pragma unroll
    for (int nt = 0; nt < 8; ++nt) vals[nt] = acc[nt][r] + vb[nt];
    if (DOLN) {
      float s1 = 0.f, s2 = 0.f;
      #pragma unroll
      for (int nt = 0; nt < 8; ++nt) { s1 += vals[nt]; s2 += vals[nt] * vals[nt]; }
      #pragma unroll
      for (int m = 1; m < 16; m <<= 1) { s1 += __shfl_xor(s1, m, 64); s2 += __shfl_xor(s2, m, 64); }
      float mu = s1 * (1.0f / 128.0f);
      float var = s2 * (1.0f / 128.0f) - mu * mu;
      float rs = rsqrtf(var + 1e-5f);
      #pragma unroll
      for (int nt = 0; nt < 8; ++nt) vals[nt] = (vals[nt] - mu) * rs * gv[nt] + bv[nt];
    }
    if (DOSILU) {
      #pragma unroll
      for (int nt = 0; nt < 8; ++nt) vals[nt] = silu_f(vals[nt]);
    }
    int row = n0 + w * 16 + lh * 4 + r;
    if (row < n) {
      float* cr = C + (size_t)row * HID;
      #pragma unroll
      for (int nt = 0; nt < 8; ++nt) {
        int col = nt * 16 + lr;
        float o = vals[nt];
        if (DORES) o += R[(size_t)row * HID + col];
        cr[col] = o;
      }
    }
  }
}

// ---------------- fused LN + dual GEMM: hn = LN(h); Pa' = perm(hn@Wa^T + b1); Pb' = perm(hn@Wb^T) ----------------
// Pa/Pb stored permuted: value for col (nt*16+lr) at offset lr*8+nt.
__global__ __launch_bounds__(256) void pab_ln(
    const float* __restrict__ Hraw, const ushort* __restrict__ Wab,
    const float* __restrict__ lg, const float* __restrict__ lbp,
    const float* __restrict__ eb1,
    float* __restrict__ Hn, float* __restrict__ Pa, float* __restrict__ Pb, int n)
{
  __shared__ float Hs[64][132];
  __shared__ ushort Al[64][136];
  const int tid = threadIdx.x;
  const int n0 = blockIdx.x * 64;

  #pragma unroll
  for (int i = 0; i < 8; ++i) {
    int s = tid + i * 256;
    int row = s >> 5, c4 = (s & 31) * 4;
    int gr = n0 + row;
    float4 v = make_float4(0.f, 0.f, 0.f, 0.f);
    if (gr < n) v = *(const float4*)(Hraw + (size_t)gr * HID + c4);
    *(float4*)&Hs[row][c4] = v;
  }
  __syncthreads();

  const int w = tid >> 6, l = tid & 63;
  const int lr = l & 15, lh = l >> 4;

  {
    const int row = w * 16 + lr;
    float s1 = 0.f, s2 = 0.f;
    #pragma unroll
    for (int j = 0; j < 8; ++j) {
      float4 v = *(float4*)&Hs[row][lh * 32 + j * 4];
      s1 += v.x + v.y + v.z + v.w;
      s2 += v.x * v.x + v.y * v.y + v.z * v.z + v.w * v.w;
    }
    s1 += __shfl_xor(s1, 16, 64); s1 += __shfl_xor(s1, 32, 64);
    s2 += __shfl_xor(s2, 16, 64); s2 += __shfl_xor(s2, 32, 64);
    float mu = s1 * (1.0f / 128.0f);
    float var = s2 * (1.0f / 128.0f) - mu * mu;
    float rs = rsqrtf(var + 1e-5f);
    int gr = n0 + row;
    #pragma unroll
    for (int j = 0; j < 8; ++j) {
      int c = lh * 32 + j * 4;
      float4 v = *(float4*)&Hs[row][c];
      float4 o;
      o.x = (v.x - mu) * rs * lg[c + 0] + lbp[c + 0];
      o.y = (v.y - mu) * rs * lg[c + 1] + lbp[c + 1];
      o.z = (v.z - mu) * rs * lg[c + 2] + lbp[c + 2];
      o.w = (v.w - mu) * rs * lg[c + 3] + lbp[c + 3];
      if (gr < n) *(float4*)(Hn + (size_t)gr * HID + c) = o;
      uint2 p;
      p.x = (uint)f2bf(o.x) | ((uint)f2bf(o.y) << 16);
      p.y = (uint)f2bf(o.z) | ((uint)f2bf(o.w) << 16);
      *(uint2*)&Al[row][c] = p;
    }
  }
  __syncthreads();

  f32x4 zf = {0.f, 0.f, 0.f, 0.f};
  f32x4 acc[16];
  #pragma unroll
  for (int nt = 0; nt < 16; ++nt) acc[nt] = zf;

  #pragma unroll
  for (int q = 0; q < 4; ++q) {
    short8 af = *(const short8*)&Al[w * 16 + lr][q * 32 + lh * 8];
    #pragma unroll
    for (int nt = 0; nt < 16; ++nt) {
      short8 bf = *(const short8*)(Wab + (size_t)(nt * 16 + lr) * HID + q * 32 + lh * 8);
      acc[nt] = __builtin_amdgcn_mfma_f32_16x16x32_bf16(af, bf, acc[nt], 0, 0, 0);
    }
  }

  float be[8];
  #pragma unroll
  for (int nt = 0; nt < 8; ++nt) be[nt] = eb1[nt * 16 + lr];

  #pragma unroll
  for (int r = 0; r < 4; ++r) {
    int row = n0 + w * 16 + lh * 4 + r;
    if (row >= n) break;
    float4 a0, a1, b0, b1;
    a0.x = acc[0][r] + be[0]; a0.y = acc[1][r] + be[1]; a0.z = acc[2][r] + be[2]; a0.w = acc[3][r] + be[3];
    a1.x = acc[4][r] + be[4]; a1.y = acc[5][r] + be[5]; a1.z = acc[6][r] + be[6]; a1.w = acc[7][r] + be[7];
    b0.x = acc[8][r];  b0.y = acc[9][r];  b0.z = acc[10][r]; b0.w = acc[11][r];
    b1.x = acc[12][r]; b1.y = acc[13][r]; b1.z = acc[14][r]; b1.w = acc[15][r];
    *(float4*)(Pa + (size_t)row * HID + lr * 8)     = a0;
    *(float4*)(Pa + (size_t)row * HID + lr * 8 + 4) = a1;
    *(float4*)(Pb + (size_t)row * HID + lr * 8)     = b0;
    *(float4*)(Pb + (size_t)row * HID + lr * 8 + 4) = b1;
  }
}

// ---------------- edge kernel: permuted Pa/Pb gathers, NATURAL-layout coalesced S atomics ----------------
__global__ __launch_bounds__(256) void edge_s(
    const float* __restrict__ Pa, const float* __restrict__ Pb,
    const ushort* __restrict__ ea_bf,
    const int* __restrict__ src_s, const int* __restrict__ dst_s,
    const ushort* __restrict__ W1c,
    const float* __restrict__ elg, const float* __restrict__ elb,
    float* __restrict__ S)
{
  const int tid = threadIdx.x;
  const int w = tid >> 6, l = tid & 63;
  const int lr = l & 15, lh = l >> 4;
  const int e0 = blockIdx.x * 64 + w * 16;

  short8 af = {0, 0, 0, 0, 0, 0, 0, 0};
  if (lh < 2) af = *(const short8*)(ea_bf + (size_t)(e0 + lr) * 16 + lh * 8);

  f32x4 zf = {0.f, 0.f, 0.f, 0.f};
  f32x4 acc[8];
  #pragma unroll
  for (int nt = 0; nt < 8; ++nt) acc[nt] = zf;
  #pragma unroll
  for (int nt = 0; nt < 8; ++nt) {
    short8 bf = *(const short8*)(W1c + (nt * 16 + lr) * 32 + lh * 8);
    acc[nt] = __builtin_amdgcn_mfma_f32_16x16x32_bf16(af, bf, acc[nt], 0, 0, 0);
  }

  int sr[4], dr[4];
  #pragma unroll
  for (int r = 0; r < 4; ++r) {
    int e = e0 + lh * 4 + r;
    sr[r] = src_s[e]; dr[r] = dst_s[e];
  }
  int first = __builtin_amdgcn_readfirstlane(sr[0]);
  int last  = __shfl(sr[3], 48, 64);
  bool uni = (first == last);

  // vectorized gathers from permuted layout: lane's 8 values contiguous at lr*8
  if (uni) {
    float4 pa0 = *(const float4*)(Pa + (size_t)first * HID + lr * 8);
    float4 pa1 = *(const float4*)(Pa + (size_t)first * HID + lr * 8 + 4);
    #pragma unroll
    for (int r = 0; r < 4; ++r) {
      float4 pb0 = *(const float4*)(Pb + (size_t)dr[r] * HID + lr * 8);
      float4 pb1 = *(const float4*)(Pb + (size_t)dr[r] * HID + lr * 8 + 4);
      acc[0][r] += pa0.x + pb0.x; acc[1][r] += pa0.y + pb0.y;
      acc[2][r] += pa0.z + pb0.z; acc[3][r] += pa0.w + pb0.w;
      acc[4][r] += pa1.x + pb1.x; acc[5][r] += pa1.y + pb1.y;
      acc[6][r] += pa1.z + pb1.z; acc[7][r] += pa1.w + pb1.w;
    }
  } else {
    #pragma unroll
    for (int r = 0; r < 4; ++r) {
      float4 pa0 = *(const float4*)(Pa + (size_t)sr[r] * HID + lr * 8);
      float4 pa1 = *(const float4*)(Pa + (size_t)sr[r] * HID + lr * 8 + 4);
      float4 pb0 = *(const float4*)(Pb + (size_t)dr[r] * HID + lr * 8);
      float4 pb1 = *(const float4*)(Pb + (size_t)dr[r] * HID + lr * 8 + 4);
      acc[0][r] += pa0.x + pb0.x; acc[1][r] += pa0.y + pb0.y;
      acc[2][r] += pa0.z + pb0.z; acc[3][r] += pa0.w + pb0.w;
      acc[4][r] += pa1.x + pb1.x; acc[5][r] += pa1.y + pb1.y;
      acc[6][r] += pa1.z + pb1.z; acc[7][r] += pa1.w + pb1.w;
    }
  }

  float gv[8], bv[8];
  #pragma unroll
  for (int nt = 0; nt < 8; ++nt) { gv[nt] = elg[nt * 16 + lr]; bv[nt] = elb[nt * 16 + lr]; }

  #pragma unroll
  for (int r = 0; r < 4; ++r) {
    float s1 = 0.f, s2 = 0.f;
    #pragma unroll
    for (int nt = 0; nt < 8; ++nt) { s1 += acc[nt][r]; s2 += acc[nt][r] * acc[nt][r]; }
    #pragma unroll
    for (int m = 1; m < 16; m <<= 1) { s1 += __shfl_xor(s1, m, 64); s2 += __shfl_xor(s2, m, 64); }
    float mu = s1 * (1.0f / 128.0f);
    float var = s2 * (1.0f / 128.0f) - mu * mu;
    float rs = rsqrtf(var + 1e-5f);
    #pragma unroll
    for (int nt = 0; nt < 8; ++nt)
      acc[nt][r] = silu_f((acc[nt][r] - mu) * rs * gv[nt] + bv[nt]);
  }

  // atomics in NATURAL layout: per instruction (fixed nt), 16 lanes -> 64 consecutive bytes
  #pragma unroll
  for (int nt = 0; nt < 8; ++nt) {
    int col = nt * 16 + lr;
    if (uni) {
      float s = acc[nt][0] + acc[nt][1] + acc[nt][2] + acc[nt][3];
      s += __shfl_xor(s, 16, 64);
      s += __shfl_xor(s, 32, 64);
      if (lh == 0)
        unsafeAtomicAdd(S + (size_t)first * HID + col, s);
    } else {
      float run = acc[nt][0];
      #pragma unroll
      for (int r = 1; r < 4; ++r) {
        if (sr[r] == sr[r - 1]) run += acc[nt][r];
        else {
          unsafeAtomicAdd(S + (size_t)sr[r - 1] * HID + col, run);
          run = acc[nt][r];
        }
      }
      unsafeAtomicAdd(S + (size_t)sr[3] * HID + col, run);
    }
  }
}

// ---------------- agg = (S_hi + S_lo) @ W2^T + deg*b2 (hi/lo bf16 split, natural layouts) ----------------
__global__ __launch_bounds__(256) void agg_gemm(
    const float* __restrict__ S, const ushort* __restrict__ W2bf,
    const float* __restrict__ b2, const int* __restrict__ deg,
    float* __restrict__ agg, int n)
{
  __shared__ ushort Ah[64][136];
  __shared__ ushort Alo[64][136];
  const int tid = threadIdx.x;
  const int n0 = blockIdx.x * 64;

  #pragma unroll
  for (int i = 0; i < 8; ++i) {
    int s = tid + i * 256;
    int row = s >> 5;
    int c4 = (s & 31) * 4;
    int gr = n0 + row;
    float4 v = make_float4(0.f, 0.f, 0.f, 0.f);
    if (gr < n) v = *(const float4*)(S + (size_t)gr * HID + c4);
    ushort hx = f2bf(v.x), hy = f2bf(v.y), hz = f2bf(v.z), hw = f2bf(v.w);
    uint2 ph, pl;
    ph.x = (uint)hx | ((uint)hy << 16);
    ph.y = (uint)hz | ((uint)hw << 16);
    pl.x = (uint)f2bf(v.x - bf2f(hx)) | ((uint)f2bf(v.y - bf2f(hy)) << 16);
    pl.y = (uint)f2bf(v.z - bf2f(hz)) | ((uint)f2bf(v.w - bf2f(hw)) << 16);
    *(uint2*)&Ah[row][c4]  = ph;
    *(uint2*)&Alo[row][c4] = pl;
  }
  __syncthreads();

  const int w = tid >> 6, l = tid & 63;
  const int lr = l & 15, lh = l >> 4;

  f32x4 zf = {0.f, 0.f, 0.f, 0.f};
  f32x4 acc[8];
  #pragma unroll
  for (int nt = 0; nt < 8; ++nt) acc[nt] = zf;

  #pragma unroll
  for (int q = 0; q < 4; ++q) {
    short8 ah = *(const short8*)&Ah[w * 16 + lr][q * 32 + lh * 8];
    short8 al = *(const short8*)&Alo[w * 16 + lr][q * 32 + lh * 8];
    #pragma unroll
    for (int nt = 0; nt < 8; ++nt) {
      short8 bf = *(const short8*)(W2bf + (size_t)(nt * 16 + lr) * HID + q * 32 + lh * 8);
      acc[nt] = __builtin_amdgcn_mfma_f32_16x16x32_bf16(ah, bf, acc[nt], 0, 0, 0);
      acc[nt] = __builtin_amdgcn_mfma_f32_16x16x32_bf16(al, bf, acc[nt], 0, 0, 0);
    }
  }

  #pragma unroll
  for (int r = 0; r < 4; ++r) {
    int row = n0 + w * 16 + lh * 4 + r;
    if (row >= n) break;
    float degf = (float)deg[row];
    float* ar = agg + (size_t)row * HID;
    #pragma unroll
    for (int nt = 0; nt < 8; ++nt) {
      int col = nt * 16 + lr;
      ar[col] = acc[nt][r] + degf * b2[col];
    }
  }
}

extern "C" void kernel_launch(void* const* d_in, const int* in_sizes, int n_in,
                              void* d_out, int out_size, void* d_ws, size_t ws_size,
                              hipStream_t stream)
{
  const float* in_h  = (const float*)d_in[0];
  const int*   edges = (const int*)d_in[1];
  const float* ea    = (const float*)d_in[2];
  const float* ei_w1 = (const float*)d_in[3];
  const float* ei_b1 = (const float*)d_in[4];
  const float* ei_w2 = (const float*)d_in[5];
  const float* ei_b2 = (const float*)d_in[6];
  const float* ng    = (const float*)d_in[7];
  const float* nbp   = (const float*)d_in[8];
  const float* ew1   = (const float*)d_in[9];
  const float* eb1   = (const float*)d_in[10];
  const float* elg   = (const float*)d_in[11];
  const float* elb   = (const float*)d_in[12];
  const float* ew2   = (const float*)d_in[13];
  const float* eb2   = (const float*)d_in[14];
  const float* nw1   = (const float*)d_in[15];
  const float* nb1   = (const float*)d_in[16];
  const float* nlg   = (const float*)d_in[17];
  const float* nlb   = (const float*)d_in[18];
  const float* nw2   = (const float*)d_in[19];
  const float* nb2   = (const float*)d_in[20];
  const float* eo_w1 = (const float*)d_in[21];
  const float* eo_b1 = (const float*)d_in[22];
  const float* eo_w2 = (const float*)d_in[23];
  const float* eo_b2 = (const float*)d_in[24];

  float* wf    = (float*)d_ws;
  float* B_h   = wf;
  float* B_hn  = wf + NNH;
  float* B_S   = wf + 2 * NNH;   // S (edge-sum, natural layout); perm alias during setup
  float* B_tmp = wf + 3 * NNH;   // Pa' / MLP intermediate
  float* B_pb  = wf + 4 * NNH;   // Pb' during edge phase; agg afterwards

  const size_t WOFF = 5 * NNH;
  ushort* wu = (ushort*)(wf + WOFF);
  // ei1@0, ei2@16384, eo1@32768, eo2@49152; per-layer base 65536 + l*104448:
  //   Wab@0 [256][128] | W2@32768 | N1@49152 [128][256] | N2@81920 | W1c@98304 [128][32]
  const size_t SOFF = WOFF + 262144;
  int* src_s = (int*)(wf + SOFF);
  int* dst_s = src_s + NE;
  int* cnt   = dst_s + NE;       // = deg
  int* cur   = cnt + NPAD;
  int* base  = cur + NPAD;
  ushort* ea_s = (ushort*)(base + NPAD);
  int* perm  = (int*)B_S;

  const int NB  = (NN + 63) / 64;
  const int EB  = NE / 64;
  const int ZB  = ((int)(NNH / 4) + 255) / 256;
  const int NEB = (NE + 255) / 256;

  const int* erow = edges;
  const int* ecol = edges + NE;

  // ---- counting sort by src (once) ----
  zero_i<<<(2 * NPAD + 255) / 256, 256, 0, stream>>>(cnt, 2 * NPAD);
  count_src<<<NEB, 256, 0, stream>>>(erow, cnt);
  scan_excl<<<1, 1024, 0, stream>>>(cnt, base, NN);
  place_edges<<<NEB, 256, 0, stream>>>(erow, ecol, base, cur, src_s, dst_s, perm);
  permute_ea_bf<<<(NE * 4 + 255) / 256, 256, 0, stream>>>((const float4*)ea, perm, ea_s);

  // ---- weight conversion to bf16 ----
  cvt4<<<256, 256, 0, stream>>>(ei_w1, ei_w2, eo_w1, eo_w2, wu);
  cvt_wab<<<512, 256, 0, stream>>>(ew1, wu + 65536);
  cvt_w1c<<<64, 256, 0, stream>>>(ew1, wu + 65536 + 98304);
  cvt_std<<<(4 * 16384 + 255) / 256, 256, 0, stream>>>(ew2, wu + 65536 + 32768, 128, 128, 16384);
  cvt_std<<<(4 * 32768 + 255) / 256, 256, 0, stream>>>(nw1, wu + 65536 + 49152, 128, 256, 32768);
  cvt_std<<<(4 * 16384 + 255) / 256, 256, 0, stream>>>(nw2, wu + 65536 + 81920, 128, 128, 16384);

  // ---- embedding_in ----
  mgemm<128, true, false, true,  false><<<NB, 256, 0, stream>>>(in_h, nullptr, wu, ei_b1, nullptr, nullptr, nullptr, B_tmp, NN);
  mgemm<128, true, false, false, false><<<NB, 256, 0, stream>>>(B_tmp, nullptr, wu + 16384, ei_b2, nullptr, nullptr, nullptr, B_h, NN);

  for (int lyr = 0; lyr < 4; ++lyr) {
    ushort* lb = wu + 65536 + lyr * 104448;
    pab_ln<<<NB, 256, 0, stream>>>(B_h, lb, ng + 128 * lyr, nbp + 128 * lyr,
        eb1 + 128 * lyr, B_hn, B_tmp, B_pb, NN);
    zero4_kernel<<<ZB, 256, 0, stream>>>((float4*)B_S, (int)(NNH / 4));
    edge_s<<<EB, 256, 0, stream>>>(B_tmp, B_pb, ea_s, src_s, dst_s,
        lb + 98304, elg + 128 * lyr, elb + 128 * lyr, B_S);
    agg_gemm<<<NB, 256, 0, stream>>>(B_S, lb + 32768, eb2 + 128 * lyr, cnt, B_pb, NN);
    mgemm<256, true, true,  true,  false><<<NB, 256, 0, stream>>>(B_hn, B_pb, lb + 49152, nb1 + 128 * lyr,
        nlg + 128 * lyr, nlb + 128 * lyr, nullptr, B_tmp, NN);
    mgemm<128, true, false, false, true ><<<NB, 256, 0, stream>>>(B_tmp, nullptr, lb + 81920, nb2 + 128 * lyr,
        nullptr, nullptr, B_hn, B_h, NN);
  }

  // ---- embedding_out ----
  mgemm<128, true, false, true,  false><<<NB, 256, 0, stream>>>(B_h, nullptr, wu + 32768, eo_b1, nullptr, nullptr, nullptr, B_tmp, NN);
  mgemm<128, true, false, false, false><<<NB, 256, 0, stream>>>(B_tmp, nullptr, wu + 49152, eo_b2, nullptr, nullptr, nullptr, (float*)d_out, NN);
}

// Round 7
// 1885.244 us; speedup vs baseline: 2.3937x; 1.0297x over previous
//
#include <hip/hip_runtime.h>
#include <math.h>

#define NN 50000
#define NE 800000
#define HID 128
#define NNH ((size_t)NN * HID)
#define NPAD 50176

typedef __attribute__((ext_vector_type(8))) short short8;
typedef __attribute__((ext_vector_type(4))) float f32x4;

__device__ __forceinline__ ushort f2bf(float f) {
  unsigned u = __float_as_uint(f);
  unsigned r = (u + 0x7fffu + ((u >> 16) & 1u)) >> 16;
  return (ushort)r;
}
__device__ __forceinline__ float bf2f(ushort h) {
  return __uint_as_float(((unsigned)h) << 16);
}
__device__ __forceinline__ float silu_f(float x) { return x / (1.0f + __expf(-x)); }

// ---------------- utility ----------------
__global__ __launch_bounds__(256) void zero_i(int* __restrict__ p, int n)
{
  int i = blockIdx.x * 256 + threadIdx.x;
  if (i < n) p[i] = 0;
}

// ---------------- counting sort of edges by src ----------------
__global__ __launch_bounds__(256) void count_src(const int* __restrict__ src, int* __restrict__ cnt)
{
  int e = blockIdx.x * 256 + threadIdx.x;
  if (e < NE) atomicAdd(&cnt[src[e]], 1);
}

__global__ __launch_bounds__(1024) void scan_excl(const int* __restrict__ cnt, int* __restrict__ base, int n)
{
  __shared__ int ws[16];
  int t = threadIdx.x;
  const int per = (n + 1023) / 1024;
  int s0 = t * per;
  int sum = 0;
  for (int i = 0; i < per; ++i) { int idx = s0 + i; if (idx < n) sum += cnt[idx]; }
  int lane = t & 63, w = t >> 6;
  int v = sum;
  #pragma unroll
  for (int m = 1; m < 64; m <<= 1) { int o = __shfl_up(v, m, 64); if (lane >= m) v += o; }
  if (lane == 63) ws[w] = v;
  __syncthreads();
  if (t == 0) { int a = 0; for (int i = 0; i < 16; ++i) { int x = ws[i]; ws[i] = a; a += x; } }
  __syncthreads();
  int run = ws[w] + v - sum;
  for (int i = 0; i < per; ++i) {
    int idx = s0 + i;
    if (idx < n) { base[idx] = run; run += cnt[idx]; }
  }
}

__global__ __launch_bounds__(256) void place_edges(const int* __restrict__ src, const int* __restrict__ dst,
    const int* __restrict__ base, int* __restrict__ cur,
    int* __restrict__ src_s, int* __restrict__ dst_s, int* __restrict__ perm)
{
  int e = blockIdx.x * 256 + threadIdx.x;
  if (e >= NE) return;
  int s = src[e];
  int p = base[s] + atomicAdd(&cur[s], 1);
  src_s[p] = s; dst_s[p] = dst[e]; perm[p] = e;
}

__global__ __launch_bounds__(256) void permute_ea_bf(const float4* __restrict__ ea,
    const int* __restrict__ perm, ushort* __restrict__ ea_s)
{
  int i = blockIdx.x * 256 + threadIdx.x;
  if (i >= NE * 4) return;
  int e = i >> 2, q = i & 3;
  float4 v = ea[(size_t)perm[e] * 4 + q];
  uint2 p;
  p.x = (uint)f2bf(v.x) | ((uint)f2bf(v.y) << 16);
  p.y = (uint)f2bf(v.z) | ((uint)f2bf(v.w) << 16);
  *(uint2*)&ea_s[(size_t)e * 16 + q * 4] = p;
}

// ---------------- weight conversion ----------------
__global__ __launch_bounds__(256) void cvt4(const float* __restrict__ s0, const float* __restrict__ s1,
    const float* __restrict__ s2, const float* __restrict__ s3, ushort* __restrict__ d)
{
  int i = blockIdx.x * 256 + threadIdx.x;
  if (i >= 65536) return;
  const float* s = (i < 16384) ? s0 : (i < 32768) ? s1 : (i < 49152) ? s2 : s3;
  d[i] = f2bf(s[i & 16383]);
}
__global__ __launch_bounds__(256) void cvt_wab(const float* __restrict__ s, ushort* __restrict__ d)
{
  int i = blockIdx.x * 256 + threadIdx.x;
  if (i >= 131072) return;
  int l = i >> 15, rem = i & 32767;
  int r = rem >> 7, c = rem & 127;
  int srow = r & 127, scol = ((r >> 7) << 7) + c;
  d[l * 104448 + r * 128 + c] = f2bf(s[(size_t)l * 34816 + srow * 272 + scol]);
}
__global__ __launch_bounds__(256) void cvt_w1c(const float* __restrict__ s, ushort* __restrict__ d)
{
  int i = blockIdx.x * 256 + threadIdx.x;
  if (i >= 16384) return;
  int l = i >> 12, rem = i & 4095;
  int r = rem >> 5, c = rem & 31;
  d[l * 104448 + r * 32 + c] = (c < 16) ? f2bf(s[(size_t)l * 34816 + r * 272 + 256 + c]) : (ushort)0;
}
__global__ __launch_bounds__(256) void cvt_std(const float* __restrict__ s, ushort* __restrict__ d,
    int rows, int cols, int lss)
{
  int i = blockIdx.x * 256 + threadIdx.x;
  int n = 4 * rows * cols;
  if (i >= n) return;
  int rc = rows * cols;
  int l = i / rc, rem = i - l * rc;
  d[l * 104448 + rem] = f2bf(s[(size_t)l * lss + rem]);
}

// ---------------- fold: W2N = N1b @ W2 (bf16), N1a (bf16), nv = N1b @ b2 (fp32) ----------------
// grid = 4*128 blocks (layer, out-row m), 128 threads (col j)
__global__ __launch_bounds__(128) void fold_w(const float* __restrict__ nw1,
    const float* __restrict__ ew2, const float* __restrict__ eb2,
    ushort* __restrict__ wu_base, float* __restrict__ nv)
{
  __shared__ float red[2];
  int bid = blockIdx.x;
  int l = bid >> 7, m = bid & 127;
  int j = threadIdx.x;
  const float* n1row = nw1 + (size_t)l * 32768 + (size_t)m * 256;
  const float* n1b = n1row + 128;
  const float* w2 = ew2 + (size_t)l * 16384;
  float s = 0.f;
  for (int k = 0; k < 128; ++k) s = fmaf(n1b[k], w2[k * 128 + j], s);
  ushort* lb = wu_base + (size_t)l * 104448;
  lb[32768 + m * 128 + j] = f2bf(s);          // W2N
  lb[49152 + m * 128 + j] = f2bf(n1row[j]);   // N1a
  float p = n1b[j] * eb2[l * 128 + j];
  #pragma unroll
  for (int mm = 1; mm < 64; mm <<= 1) p += __shfl_xor(p, mm, 64);
  if ((j & 63) == 0) red[j >> 6] = p;
  __syncthreads();
  if (j == 0) nv[l * 128 + m] = red[0] + red[1];
}

// ---------------- MFMA GEMM: C = [R +] act(ln?(A @ W^T + bias)) ----------------
template<int KT, bool DOBIAS, bool DOLN, bool DOSILU, bool DORES>
__global__ __launch_bounds__(256) void mgemm(
    const float* __restrict__ A0, const float* __restrict__ A1,
    const ushort* __restrict__ Wbf, const float* __restrict__ bias,
    const float* __restrict__ lng, const float* __restrict__ lnb,
    const float* __restrict__ R, float* __restrict__ C, int n)
{
  constexpr int LDA = (KT == 256) ? 264 : 136;
  __shared__ ushort Al[64][LDA];
  const int tid = threadIdx.x;
  const int n0 = blockIdx.x * 64;

  constexpr int SPR = KT / 4;
  #pragma unroll
  for (int i = 0; i < (64 * KT / 4) / 256; ++i) {
    int s = tid + i * 256;
    int row = s / SPR;
    int c4 = (s % SPR) * 4;
    int gr = n0 + row;
    float4 v = make_float4(0.f, 0.f, 0.f, 0.f);
    if (gr < n) {
      if (KT == 256)
        v = (c4 < 128) ? *(const float4*)(A0 + (size_t)gr * HID + c4)
                       : *(const float4*)(A1 + (size_t)gr * HID + (c4 - 128));
      else
        v = *(const float4*)(A0 + (size_t)gr * HID + c4);
    }
    uint2 p;
    p.x = (uint)f2bf(v.x) | ((uint)f2bf(v.y) << 16);
    p.y = (uint)f2bf(v.z) | ((uint)f2bf(v.w) << 16);
    *(uint2*)&Al[row][c4] = p;
  }
  __syncthreads();

  const int w = tid >> 6, l = tid & 63;
  const int lr = l & 15, lh = l >> 4;

  f32x4 zf = {0.f, 0.f, 0.f, 0.f};
  f32x4 acc[8];
  #pragma unroll
  for (int nt = 0; nt < 8; ++nt) acc[nt] = zf;

  #pragma unroll
  for (int q = 0; q < KT / 32; ++q) {
    short8 af = *(const short8*)&Al[w * 16 + lr][q * 32 + lh * 8];
    #pragma unroll
    for (int nt = 0; nt < 8; ++nt) {
      short8 bf = *(const short8*)(Wbf + (size_t)(nt * 16 + lr) * KT + q * 32 + lh * 8);
      acc[nt] = __builtin_amdgcn_mfma_f32_16x16x32_bf16(af, bf, acc[nt], 0, 0, 0);
    }
  }

  float vb[8], gv[8], bv[8];
  #pragma unroll
  for (int nt = 0; nt < 8; ++nt) {
    int col = nt * 16 + lr;
    vb[nt] = DOBIAS ? bias[col] : 0.f;
    if (DOLN) { gv[nt] = lng[col]; bv[nt] = lnb[col]; }
  }

  #pragma unroll
  for (int r = 0; r < 4; ++r) {
    float vals[8];
    #pragma unroll
    for (int nt = 0; nt < 8; ++nt) vals[nt] = acc[nt][r] + vb[nt];
    if (DOLN) {
      float s1 = 0.f, s2 = 0.f;
      #pragma unroll
      for (int nt = 0; nt < 8; ++nt) { s1 += vals[nt]; s2 += vals[nt] * vals[nt]; }
      #pragma unroll
      for (int m = 1; m < 16; m <<= 1) { s1 += __shfl_xor(s1, m, 64); s2 += __shfl_xor(s2, m, 64); }
      float mu = s1 * (1.0f / 128.0f);
      float var = s2 * (1.0f / 128.0f) - mu * mu;
      float rs = rsqrtf(var + 1e-5f);
      #pragma unroll
      for (int nt = 0; nt < 8; ++nt) vals[nt] = (vals[nt] - mu) * rs * gv[nt] + bv[nt];
    }
    if (DOSILU) {
      #pragma unroll
      for (int nt = 0; nt < 8; ++nt) vals[nt] = silu_f(vals[nt]);
    }
    int row = n0 + w * 16 + lh * 4 + r;
    if (row < n) {
      float* cr = C + (size_t)row * HID;
      #pragma unroll
      for (int nt = 0; nt < 8; ++nt) {
        int col = nt * 16 + lr;
        float o = vals[nt];
        if (DORES) o += R[(size_t)row * HID + col];
        cr[col] = o;
      }
    }
  }
}

// ---------------- fused LN + dual GEMM + S-zero ----------------
// hn = LN(h); Pa' = perm(hn@Wa^T + b1); Pb' = perm(hn@Wb^T); S[rows] = 0
__global__ __launch_bounds__(256) void pab_ln(
    const float* __restrict__ Hraw, const ushort* __restrict__ Wab,
    const float* __restrict__ lg, const float* __restrict__ lbp,
    const float* __restrict__ eb1,
    float* __restrict__ Hn, float* __restrict__ Pa, float* __restrict__ Pb,
    float* __restrict__ Sz, int n)
{
  __shared__ float Hs[64][132];
  __shared__ ushort Al[64][136];
  const int tid = threadIdx.x;
  const int n0 = blockIdx.x * 64;

  #pragma unroll
  for (int i = 0; i < 8; ++i) {
    int s = tid + i * 256;
    int row = s >> 5, c4 = (s & 31) * 4;
    int gr = n0 + row;
    float4 v = make_float4(0.f, 0.f, 0.f, 0.f);
    if (gr < n) {
      v = *(const float4*)(Hraw + (size_t)gr * HID + c4);
      *(float4*)(Sz + (size_t)gr * HID + c4) = make_float4(0.f, 0.f, 0.f, 0.f);
    }
    *(float4*)&Hs[row][c4] = v;
  }
  __syncthreads();

  const int w = tid >> 6, l = tid & 63;
  const int lr = l & 15, lh = l >> 4;

  {
    const int row = w * 16 + lr;
    float s1 = 0.f, s2 = 0.f;
    #pragma unroll
    for (int j = 0; j < 8; ++j) {
      float4 v = *(float4*)&Hs[row][lh * 32 + j * 4];
      s1 += v.x + v.y + v.z + v.w;
      s2 += v.x * v.x + v.y * v.y + v.z * v.z + v.w * v.w;
    }
    s1 += __shfl_xor(s1, 16, 64); s1 += __shfl_xor(s1, 32, 64);
    s2 += __shfl_xor(s2, 16, 64); s2 += __shfl_xor(s2, 32, 64);
    float mu = s1 * (1.0f / 128.0f);
    float var = s2 * (1.0f / 128.0f) - mu * mu;
    float rs = rsqrtf(var + 1e-5f);
    int gr = n0 + row;
    #pragma unroll
    for (int j = 0; j < 8; ++j) {
      int c = lh * 32 + j * 4;
      float4 v = *(float4*)&Hs[row][c];
      float4 o;
      o.x = (v.x - mu) * rs * lg[c + 0] + lbp[c + 0];
      o.y = (v.y - mu) * rs * lg[c + 1] + lbp[c + 1];
      o.z = (v.z - mu) * rs * lg[c + 2] + lbp[c + 2];
      o.w = (v.w - mu) * rs * lg[c + 3] + lbp[c + 3];
      if (gr < n) *(float4*)(Hn + (size_t)gr * HID + c) = o;
      uint2 p;
      p.x = (uint)f2bf(o.x) | ((uint)f2bf(o.y) << 16);
      p.y = (uint)f2bf(o.z) | ((uint)f2bf(o.w) << 16);
      *(uint2*)&Al[row][c] = p;
    }
  }
  __syncthreads();

  f32x4 zf = {0.f, 0.f, 0.f, 0.f};
  f32x4 acc[16];
  #pragma unroll
  for (int nt = 0; nt < 16; ++nt) acc[nt] = zf;

  #pragma unroll
  for (int q = 0; q < 4; ++q) {
    short8 af = *(const short8*)&Al[w * 16 + lr][q * 32 + lh * 8];
    #pragma unroll
    for (int nt = 0; nt < 16; ++nt) {
      short8 bf = *(const short8*)(Wab + (size_t)(nt * 16 + lr) * HID + q * 32 + lh * 8);
      acc[nt] = __builtin_amdgcn_mfma_f32_16x16x32_bf16(af, bf, acc[nt], 0, 0, 0);
    }
  }

  float be[8];
  #pragma unroll
  for (int nt = 0; nt < 8; ++nt) be[nt] = eb1[nt * 16 + lr];

  #pragma unroll
  for (int r = 0; r < 4; ++r) {
    int row = n0 + w * 16 + lh * 4 + r;
    if (row >= n) break;
    float4 a0, a1, b0, b1;
    a0.x = acc[0][r] + be[0]; a0.y = acc[1][r] + be[1]; a0.z = acc[2][r] + be[2]; a0.w = acc[3][r] + be[3];
    a1.x = acc[4][r] + be[4]; a1.y = acc[5][r] + be[5]; a1.z = acc[6][r] + be[6]; a1.w = acc[7][r] + be[7];
    b0.x = acc[8][r];  b0.y = acc[9][r];  b0.z = acc[10][r]; b0.w = acc[11][r];
    b1.x = acc[12][r]; b1.y = acc[13][r]; b1.z = acc[14][r]; b1.w = acc[15][r];
    *(float4*)(Pa + (size_t)row * HID + lr * 8)     = a0;
    *(float4*)(Pa + (size_t)row * HID + lr * 8 + 4) = a1;
    *(float4*)(Pb + (size_t)row * HID + lr * 8)     = b0;
    *(float4*)(Pb + (size_t)row * HID + lr * 8 + 4) = b1;
  }
}

// ---------------- edge kernel: 2 groups/wave, software-pipelined ----------------
__global__ __launch_bounds__(256) void edge_s(
    const float* __restrict__ Pa, const float* __restrict__ Pb,
    const ushort* __restrict__ ea_bf,
    const int* __restrict__ src_s, const int* __restrict__ dst_s,
    const ushort* __restrict__ W1c,
    const float* __restrict__ elg, const float* __restrict__ elb,
    float* __restrict__ S)
{
  const int tid = threadIdx.x;
  const int w = tid >> 6, l = tid & 63;
  const int lr = l & 15, lh = l >> 4;
  const int e0 = blockIdx.x * 128 + w * 32;

  short8 af0 = {0, 0, 0, 0, 0, 0, 0, 0};
  short8 af1 = {0, 0, 0, 0, 0, 0, 0, 0};
  if (lh < 2) {
    af0 = *(const short8*)(ea_bf + (size_t)(e0 + lr) * 16 + lh * 8);
    af1 = *(const short8*)(ea_bf + (size_t)(e0 + 16 + lr) * 16 + lh * 8);
  }

  f32x4 zf = {0.f, 0.f, 0.f, 0.f};
  f32x4 acc0[8], acc1[8];
  #pragma unroll
  for (int nt = 0; nt < 8; ++nt) { acc0[nt] = zf; acc1[nt] = zf; }
  #pragma unroll
  for (int nt = 0; nt < 8; ++nt) {
    short8 bf = *(const short8*)(W1c + (nt * 16 + lr) * 32 + lh * 8);
    acc0[nt] = __builtin_amdgcn_mfma_f32_16x16x32_bf16(af0, bf, acc0[nt], 0, 0, 0);
    acc1[nt] = __builtin_amdgcn_mfma_f32_16x16x32_bf16(af1, bf, acc1[nt], 0, 0, 0);
  }

  int sr0[4], dr0[4], sr1[4], dr1[4];
  #pragma unroll
  for (int r = 0; r < 4; ++r) {
    int e = e0 + lh * 4 + r;
    sr0[r] = src_s[e];      dr0[r] = dst_s[e];
    sr1[r] = src_s[e + 16]; dr1[r] = dst_s[e + 16];
  }
  int f0 = __builtin_amdgcn_readfirstlane(sr0[0]);
  bool uni0 = (f0 == __shfl(sr0[3], 48, 64));
  int f1 = __builtin_amdgcn_readfirstlane(sr1[0]);
  bool uni1 = (f1 == __shfl(sr1[3], 48, 64));

  // group 0: gather + accumulate immediately
  #pragma unroll
  for (int r = 0; r < 4; ++r) {
    const float* pa = Pa + (size_t)sr0[r] * HID + lr * 8;
    const float* pb = Pb + (size_t)dr0[r] * HID + lr * 8;
    float4 pa0 = *(const float4*)pa, pa1 = *(const float4*)(pa + 4);
    float4 pb0 = *(const float4*)pb, pb1 = *(const float4*)(pb + 4);
    acc0[0][r] += pa0.x + pb0.x; acc0[1][r] += pa0.y + pb0.y;
    acc0[2][r] += pa0.z + pb0.z; acc0[3][r] += pa0.w + pb0.w;
    acc0[4][r] += pa1.x + pb1.x; acc0[5][r] += pa1.y + pb1.y;
    acc0[6][r] += pa1.z + pb1.z; acc0[7][r] += pa1.w + pb1.w;
  }

  // group 1: issue gathers into temps now; consume after group-0 processing
  float4 t_pa0[4], t_pa1[4], t_pb0[4], t_pb1[4];
  #pragma unroll
  for (int r = 0; r < 4; ++r) {
    const float* pa = Pa + (size_t)sr1[r] * HID + lr * 8;
    const float* pb = Pb + (size_t)dr1[r] * HID + lr * 8;
    t_pa0[r] = *(const float4*)pa; t_pa1[r] = *(const float4*)(pa + 4);
    t_pb0[r] = *(const float4*)pb; t_pb1[r] = *(const float4*)(pb + 4);
  }

  float gv[8], bv[8];
  #pragma unroll
  for (int nt = 0; nt < 8; ++nt) { gv[nt] = elg[nt * 16 + lr]; bv[nt] = elb[nt * 16 + lr]; }

  auto ln_silu = [&](f32x4* acc) {
    #pragma unroll
    for (int r = 0; r < 4; ++r) {
      float s1 = 0.f, s2 = 0.f;
      #pragma unroll
      for (int nt = 0; nt < 8; ++nt) { s1 += acc[nt][r]; s2 += acc[nt][r] * acc[nt][r]; }
      #pragma unroll
      for (int m = 1; m < 16; m <<= 1) { s1 += __shfl_xor(s1, m, 64); s2 += __shfl_xor(s2, m, 64); }
      float mu = s1 * (1.0f / 128.0f);
      float var = s2 * (1.0f / 128.0f) - mu * mu;
      float rs = rsqrtf(var + 1e-5f);
      #pragma unroll
      for (int nt = 0; nt < 8; ++nt)
        acc[nt][r] = silu_f((acc[nt][r] - mu) * rs * gv[nt] + bv[nt]);
    }
  };
  auto scatter = [&](f32x4* acc, int* sr, bool uni, int first) {
    #pragma unroll
    for (int nt = 0; nt < 8; ++nt) {
      int col = nt * 16 + lr;
      if (uni) {
        float s = acc[nt][0] + acc[nt][1] + acc[nt][2] + acc[nt][3];
        s += __shfl_xor(s, 16, 64);
        s += __shfl_xor(s, 32, 64);
        if (lh == 0)
          unsafeAtomicAdd(S + (size_t)first * HID + col, s);
      } else {
        float run = acc[nt][0];
        #pragma unroll
        for (int r = 1; r < 4; ++r) {
          if (sr[r] == sr[r - 1]) run += acc[nt][r];
          else {
            unsafeAtomicAdd(S + (size_t)sr[r - 1] * HID + col, run);
            run = acc[nt][r];
          }
        }
        unsafeAtomicAdd(S + (size_t)sr[3] * HID + col, run);
      }
    }
  };

  ln_silu(acc0);
  scatter(acc0, sr0, uni0, f0);

  // group 1: accumulate (waits on the prefetched loads), then process
  #pragma unroll
  for (int r = 0; r < 4; ++r) {
    acc1[0][r] += t_pa0[r].x + t_pb0[r].x; acc1[1][r] += t_pa0[r].y + t_pb0[r].y;
    acc1[2][r] += t_pa0[r].z + t_pb0[r].z; acc1[3][r] += t_pa0[r].w + t_pb0[r].w;
    acc1[4][r] += t_pa1[r].x + t_pb1[r].x; acc1[5][r] += t_pa1[r].y + t_pb1[r].y;
    acc1[6][r] += t_pa1[r].z + t_pb1[r].z; acc1[7][r] += t_pa1[r].w + t_pb1[r].w;
  }
  ln_silu(acc1);
  scatter(acc1, sr1, uni1, f1);
}

// ---------------- node MLP part 1 (folded): tmp = SiLU(LN(hn@N1a^T + Shi@W2N^T + Slo@W2N^T + deg*nv + nb1)) ----------------
__global__ __launch_bounds__(256) void node1_gemm(
    const float* __restrict__ Hn, const float* __restrict__ S,
    const ushort* __restrict__ N1a, const ushort* __restrict__ W2N,
    const float* __restrict__ nb1, const float* __restrict__ nv,
    const int* __restrict__ deg,
    const float* __restrict__ lng, const float* __restrict__ lnb,
    float* __restrict__ C, int n)
{
  __shared__ ushort Ahn[64][136];
  __shared__ ushort Ah[64][136];
  __shared__ ushort Alo[64][136];
  const int tid = threadIdx.x;
  const int n0 = blockIdx.x * 64;

  #pragma unroll
  for (int i = 0; i < 8; ++i) {
    int s = tid + i * 256;
    int row = s >> 5, c4 = (s & 31) * 4;
    int gr = n0 + row;
    float4 vh = make_float4(0.f, 0.f, 0.f, 0.f);
    float4 vs = make_float4(0.f, 0.f, 0.f, 0.f);
    if (gr < n) {
      vh = *(const float4*)(Hn + (size_t)gr * HID + c4);
      vs = *(const float4*)(S + (size_t)gr * HID + c4);
    }
    uint2 ph;
    ph.x = (uint)f2bf(vh.x) | ((uint)f2bf(vh.y) << 16);
    ph.y = (uint)f2bf(vh.z) | ((uint)f2bf(vh.w) << 16);
    *(uint2*)&Ahn[row][c4] = ph;
    ushort hx = f2bf(vs.x), hy = f2bf(vs.y), hz = f2bf(vs.z), hw = f2bf(vs.w);
    uint2 ps, pl;
    ps.x = (uint)hx | ((uint)hy << 16);
    ps.y = (uint)hz | ((uint)hw << 16);
    pl.x = (uint)f2bf(vs.x - bf2f(hx)) | ((uint)f2bf(vs.y - bf2f(hy)) << 16);
    pl.y = (uint)f2bf(vs.z - bf2f(hz)) | ((uint)f2bf(vs.w - bf2f(hw)) << 16);
    *(uint2*)&Ah[row][c4]  = ps;
    *(uint2*)&Alo[row][c4] = pl;
  }
  __syncthreads();

  const int w = tid >> 6, l = tid & 63;
  const int lr = l & 15, lh = l >> 4;

  f32x4 zf = {0.f, 0.f, 0.f, 0.f};
  f32x4 acc[8];
  #pragma unroll
  for (int nt = 0; nt < 8; ++nt) acc[nt] = zf;

  #pragma unroll
  for (int q = 0; q < 4; ++q) {
    short8 an = *(const short8*)&Ahn[w * 16 + lr][q * 32 + lh * 8];
    short8 ah = *(const short8*)&Ah[w * 16 + lr][q * 32 + lh * 8];
    short8 al = *(const short8*)&Alo[w * 16 + lr][q * 32 + lh * 8];
    #pragma unroll
    for (int nt = 0; nt < 8; ++nt) {
      short8 b1f = *(const short8*)(N1a + (size_t)(nt * 16 + lr) * HID + q * 32 + lh * 8);
      short8 b2f = *(const short8*)(W2N + (size_t)(nt * 16 + lr) * HID + q * 32 + lh * 8);
      acc[nt] = __builtin_amdgcn_mfma_f32_16x16x32_bf16(an, b1f, acc[nt], 0, 0, 0);
      acc[nt] = __builtin_amdgcn_mfma_f32_16x16x32_bf16(ah, b2f, acc[nt], 0, 0, 0);
      acc[nt] = __builtin_amdgcn_mfma_f32_16x16x32_bf16(al, b2f, acc[nt], 0, 0, 0);
    }
  }

  float vb[8], vn[8], gv[8], bv[8];
  #pragma unroll
  for (int nt = 0; nt < 8; ++nt) {
    int col = nt * 16 + lr;
    vb[nt] = nb1[col]; vn[nt] = nv[col];
    gv[nt] = lng[col]; bv[nt] = lnb[col];
  }

  #pragma unroll
  for (int r = 0; r < 4; ++r) {
    int row = n0 + w * 16 + lh * 4 + r;
    float degf = (row < n) ? (float)deg[row] : 0.f;
    float vals[8];
    #pragma unroll
    for (int nt = 0; nt < 8; ++nt) vals[nt] = acc[nt][r] + vb[nt] + degf * vn[nt];
    float s1 = 0.f, s2 = 0.f;
    #pragma unroll
    for (int nt = 0; nt < 8; ++nt) { s1 += vals[nt]; s2 += vals[nt] * vals[nt]; }
    #pragma unroll
    for (int m = 1; m < 16; m <<= 1) { s1 += __shfl_xor(s1, m, 64); s2 += __shfl_xor(s2, m, 64); }
    float mu = s1 * (1.0f / 128.0f);
    float var = s2 * (1.0f / 128.0f) - mu * mu;
    float rs = rsqrtf(var + 1e-5f);
    if (row < n) {
      float* cr = C + (size_t)row * HID;
      #pragma unroll
      for (int nt = 0; nt < 8; ++nt) {
        int col = nt * 16 + lr;
        cr[col] = silu_f((vals[nt] - mu) * rs * gv[nt] + bv[nt]);
      }
    }
  }
}

extern "C" void kernel_launch(void* const* d_in, const int* in_sizes, int n_in,
                              void* d_out, int out_size, void* d_ws, size_t ws_size,
                              hipStream_t stream)
{
  const float* in_h  = (const float*)d_in[0];
  const int*   edges = (const int*)d_in[1];
  const float* ea    = (const float*)d_in[2];
  const float* ei_w1 = (const float*)d_in[3];
  const float* ei_b1 = (const float*)d_in[4];
  const float* ei_w2 = (const float*)d_in[5];
  const float* ei_b2 = (const float*)d_in[6];
  const float* ng    = (const float*)d_in[7];
  const float* nbp   = (const float*)d_in[8];
  const float* ew1   = (const float*)d_in[9];
  const float* eb1   = (const float*)d_in[10];
  const float* elg   = (const float*)d_in[11];
  const float* elb   = (const float*)d_in[12];
  const float* ew2   = (const float*)d_in[13];
  const float* eb2   = (const float*)d_in[14];
  const float* nw1   = (const float*)d_in[15];
  const float* nb1   = (const float*)d_in[16];
  const float* nlg   = (const float*)d_in[17];
  const float* nlb   = (const float*)d_in[18];
  const float* nw2   = (const float*)d_in[19];
  const float* nb2   = (const float*)d_in[20];
  const float* eo_w1 = (const float*)d_in[21];
  const float* eo_b1 = (const float*)d_in[22];
  const float* eo_w2 = (const float*)d_in[23];
  const float* eo_b2 = (const float*)d_in[24];

  float* wf    = (float*)d_ws;
  float* B_h   = wf;
  float* B_hn  = wf + NNH;
  float* B_S   = wf + 2 * NNH;   // S (edge-sum, natural layout); perm alias during setup
  float* B_tmp = wf + 3 * NNH;   // Pa' / MLP intermediate
  float* B_pb  = wf + 4 * NNH;   // Pb'

  const size_t WOFF = 5 * NNH;
  ushort* wu = (ushort*)(wf + WOFF);
  // ei1@0, ei2@16384, eo1@32768, eo2@49152; per-layer base 65536 + l*104448:
  //   Wab@0 [256][128] | W2N@32768 | N1a@49152 | N2@81920 | W1c@98304 [128][32]
  const size_t SOFF = WOFF + 262144;
  int* src_s = (int*)(wf + SOFF);
  int* dst_s = src_s + NE;
  int* cnt   = dst_s + NE;       // = deg
  int* cur   = cnt + NPAD;
  int* base  = cur + NPAD;
  ushort* ea_s = (ushort*)(base + NPAD);
  float* nvb = (float*)(ea_s + (size_t)NE * 16);   // 4*128 fp32
  int* perm  = (int*)B_S;

  const int NB  = (NN + 63) / 64;
  const int EB  = NE / 128;
  const int NEB = (NE + 255) / 256;

  const int* erow = edges;
  const int* ecol = edges + NE;

  // ---- counting sort by src (once) ----
  zero_i<<<(2 * NPAD + 255) / 256, 256, 0, stream>>>(cnt, 2 * NPAD);
  count_src<<<NEB, 256, 0, stream>>>(erow, cnt);
  scan_excl<<<1, 1024, 0, stream>>>(cnt, base, NN);
  place_edges<<<NEB, 256, 0, stream>>>(erow, ecol, base, cur, src_s, dst_s, perm);
  permute_ea_bf<<<(NE * 4 + 255) / 256, 256, 0, stream>>>((const float4*)ea, perm, ea_s);

  // ---- weight conversion / folding ----
  cvt4<<<256, 256, 0, stream>>>(ei_w1, ei_w2, eo_w1, eo_w2, wu);
  cvt_wab<<<512, 256, 0, stream>>>(ew1, wu + 65536);
  cvt_w1c<<<64, 256, 0, stream>>>(ew1, wu + 65536 + 98304);
  cvt_std<<<(4 * 16384 + 255) / 256, 256, 0, stream>>>(nw2, wu + 65536 + 81920, 128, 128, 16384);
  fold_w<<<512, 128, 0, stream>>>(nw1, ew2, eb2, wu + 65536, nvb);

  // ---- embedding_in ----
  mgemm<128, true, false, true,  false><<<NB, 256, 0, stream>>>(in_h, nullptr, wu, ei_b1, nullptr, nullptr, nullptr, B_tmp, NN);
  mgemm<128, true, false, false, false><<<NB, 256, 0, stream>>>(B_tmp, nullptr, wu + 16384, ei_b2, nullptr, nullptr, nullptr, B_h, NN);

  for (int lyr = 0; lyr < 4; ++lyr) {
    ushort* lb = wu + 65536 + lyr * 104448;
    pab_ln<<<NB, 256, 0, stream>>>(B_h, lb, ng + 128 * lyr, nbp + 128 * lyr,
        eb1 + 128 * lyr, B_hn, B_tmp, B_pb, B_S, NN);
    edge_s<<<EB, 256, 0, stream>>>(B_tmp, B_pb, ea_s, src_s, dst_s,
        lb + 98304, elg + 128 * lyr, elb + 128 * lyr, B_S);
    node1_gemm<<<NB, 256, 0, stream>>>(B_hn, B_S, lb + 49152, lb + 32768,
        nb1 + 128 * lyr, nvb + 128 * lyr, cnt,
        nlg + 128 * lyr, nlb + 128 * lyr, B_tmp, NN);
    mgemm<128, true, false, false, true ><<<NB, 256, 0, stream>>>(B_tmp, nullptr, lb + 81920, nb2 + 128 * lyr,
        nullptr, nullptr, B_hn, B_h, NN);
  }

  // ---- embedding_out ----
  mgemm<128, true, false, true,  false><<<NB, 256, 0, stream>>>(B_h, nullptr, wu + 32768, eo_b1, nullptr, nullptr, nullptr, B_tmp, NN);
  mgemm<128, true, false, false, false><<<NB, 256, 0, stream>>>(B_tmp, nullptr, wu + 49152, eo_b2, nullptr, nullptr, nullptr, (float*)d_out, NN);
}

// Round 8
// 1461.286 us; speedup vs baseline: 3.0882x; 1.2901x over previous
//
#include <hip/hip_runtime.h>
#include <math.h>

#define NN 50000
#define NE 800000
#define HID 128
#define NNH ((size_t)NN * HID)
#define NPAD 50176

typedef __attribute__((ext_vector_type(8))) short short8;
typedef __attribute__((ext_vector_type(4))) float f32x4;

__device__ __forceinline__ ushort f2bf(float f) {
  unsigned u = __float_as_uint(f);
  unsigned r = (u + 0x7fffu + ((u >> 16) & 1u)) >> 16;
  return (ushort)r;
}
__device__ __forceinline__ float bf2f(ushort h) {
  return __uint_as_float(((unsigned)h) << 16);
}
__device__ __forceinline__ float silu_f(float x) { return x / (1.0f + __expf(-x)); }

// ---------------- utility ----------------
__global__ __launch_bounds__(256) void zero_i(int* __restrict__ p, int n)
{
  int i = blockIdx.x * 256 + threadIdx.x;
  if (i < n) p[i] = 0;
}

// ---------------- counting sort of edges by src ----------------
__global__ __launch_bounds__(256) void count_src(const int* __restrict__ src, int* __restrict__ cnt)
{
  int e = blockIdx.x * 256 + threadIdx.x;
  if (e < NE) atomicAdd(&cnt[src[e]], 1);
}

__global__ __launch_bounds__(1024) void scan_excl(const int* __restrict__ cnt, int* __restrict__ base, int n)
{
  __shared__ int ws[16];
  int t = threadIdx.x;
  const int per = (n + 1023) / 1024;
  int s0 = t * per;
  int sum = 0;
  for (int i = 0; i < per; ++i) { int idx = s0 + i; if (idx < n) sum += cnt[idx]; }
  int lane = t & 63, w = t >> 6;
  int v = sum;
  #pragma unroll
  for (int m = 1; m < 64; m <<= 1) { int o = __shfl_up(v, m, 64); if (lane >= m) v += o; }
  if (lane == 63) ws[w] = v;
  __syncthreads();
  if (t == 0) { int a = 0; for (int i = 0; i < 16; ++i) { int x = ws[i]; ws[i] = a; a += x; } }
  __syncthreads();
  int run = ws[w] + v - sum;
  for (int i = 0; i < per; ++i) {
    int idx = s0 + i;
    if (idx < n) { base[idx] = run; run += cnt[idx]; }
  }
}

__global__ __launch_bounds__(256) void place_edges(const int* __restrict__ src, const int* __restrict__ dst,
    const int* __restrict__ base, int* __restrict__ cur,
    int* __restrict__ dst_s, int* __restrict__ perm)
{
  int e = blockIdx.x * 256 + threadIdx.x;
  if (e >= NE) return;
  int s = src[e];
  int p = base[s] + atomicAdd(&cur[s], 1);
  dst_s[p] = dst[e]; perm[p] = e;
}

__global__ __launch_bounds__(256) void permute_ea_bf(const float4* __restrict__ ea,
    const int* __restrict__ perm, ushort* __restrict__ ea_s)
{
  int i = blockIdx.x * 256 + threadIdx.x;
  if (i >= NE * 4) return;
  int e = i >> 2, q = i & 3;
  float4 v = ea[(size_t)perm[e] * 4 + q];
  uint2 p;
  p.x = (uint)f2bf(v.x) | ((uint)f2bf(v.y) << 16);
  p.y = (uint)f2bf(v.z) | ((uint)f2bf(v.w) << 16);
  *(uint2*)&ea_s[(size_t)e * 16 + q * 4] = p;
}

// ---------------- weight conversion ----------------
__global__ __launch_bounds__(256) void cvt4(const float* __restrict__ s0, const float* __restrict__ s1,
    const float* __restrict__ s2, const float* __restrict__ s3, ushort* __restrict__ d)
{
  int i = blockIdx.x * 256 + threadIdx.x;
  if (i >= 65536) return;
  const float* s = (i < 16384) ? s0 : (i < 32768) ? s1 : (i < 49152) ? s2 : s3;
  d[i] = f2bf(s[i & 16383]);
}
__global__ __launch_bounds__(256) void cvt_wab(const float* __restrict__ s, ushort* __restrict__ d)
{
  int i = blockIdx.x * 256 + threadIdx.x;
  if (i >= 131072) return;
  int l = i >> 15, rem = i & 32767;
  int r = rem >> 7, c = rem & 127;
  int srow = r & 127, scol = ((r >> 7) << 7) + c;
  d[l * 104448 + r * 128 + c] = f2bf(s[(size_t)l * 34816 + srow * 272 + scol]);
}
__global__ __launch_bounds__(256) void cvt_std(const float* __restrict__ s, ushort* __restrict__ d,
    int rows, int cols, int lss)
{
  int i = blockIdx.x * 256 + threadIdx.x;
  int n = 4 * rows * cols;
  if (i >= n) return;
  int rc = rows * cols;
  int l = i / rc, rem = i - l * rc;
  d[l * 104448 + rem] = f2bf(s[(size_t)l * lss + rem]);
}

// ---------------- fold: W2N = N1b @ W2 (bf16), N1a (bf16), nv = N1b @ b2 (fp32) ----------------
__global__ __launch_bounds__(128) void fold_w(const float* __restrict__ nw1,
    const float* __restrict__ ew2, const float* __restrict__ eb2,
    ushort* __restrict__ wu_base, float* __restrict__ nv)
{
  __shared__ float red[2];
  int bid = blockIdx.x;
  int l = bid >> 7, m = bid & 127;
  int j = threadIdx.x;
  const float* n1row = nw1 + (size_t)l * 32768 + (size_t)m * 256;
  const float* n1b = n1row + 128;
  const float* w2 = ew2 + (size_t)l * 16384;
  float s = 0.f;
  for (int k = 0; k < 128; ++k) s = fmaf(n1b[k], w2[k * 128 + j], s);
  ushort* lb = wu_base + (size_t)l * 104448;
  lb[32768 + m * 128 + j] = f2bf(s);          // W2N
  lb[49152 + m * 128 + j] = f2bf(n1row[j]);   // N1a
  float p = n1b[j] * eb2[l * 128 + j];
  #pragma unroll
  for (int mm = 1; mm < 64; mm <<= 1) p += __shfl_xor(p, mm, 64);
  if ((j & 63) == 0) red[j >> 6] = p;
  __syncthreads();
  if (j == 0) nv[l * 128 + m] = red[0] + red[1];
}

// ---------------- MFMA GEMM: C = [R +] act(ln?(A @ W^T + bias)) ----------------
template<int KT, bool DOBIAS, bool DOLN, bool DOSILU, bool DORES>
__global__ __launch_bounds__(256) void mgemm(
    const float* __restrict__ A0, const float* __restrict__ A1,
    const ushort* __restrict__ Wbf, const float* __restrict__ bias,
    const float* __restrict__ lng, const float* __restrict__ lnb,
    const float* __restrict__ R, float* __restrict__ C, int n)
{
  constexpr int LDA = (KT == 256) ? 264 : 136;
  __shared__ ushort Al[64][LDA];
  const int tid = threadIdx.x;
  const int n0 = blockIdx.x * 64;

  constexpr int SPR = KT / 4;
  #pragma unroll
  for (int i = 0; i < (64 * KT / 4) / 256; ++i) {
    int s = tid + i * 256;
    int row = s / SPR;
    int c4 = (s % SPR) * 4;
    int gr = n0 + row;
    float4 v = make_float4(0.f, 0.f, 0.f, 0.f);
    if (gr < n) {
      if (KT == 256)
        v = (c4 < 128) ? *(const float4*)(A0 + (size_t)gr * HID + c4)
                       : *(const float4*)(A1 + (size_t)gr * HID + (c4 - 128));
      else
        v = *(const float4*)(A0 + (size_t)gr * HID + c4);
    }
    uint2 p;
    p.x = (uint)f2bf(v.x) | ((uint)f2bf(v.y) << 16);
    p.y = (uint)f2bf(v.z) | ((uint)f2bf(v.w) << 16);
    *(uint2*)&Al[row][c4] = p;
  }
  __syncthreads();

  const int w = tid >> 6, l = tid & 63;
  const int lr = l & 15, lh = l >> 4;

  f32x4 zf = {0.f, 0.f, 0.f, 0.f};
  f32x4 acc[8];
  #pragma unroll
  for (int nt = 0; nt < 8; ++nt) acc[nt] = zf;

  #pragma unroll
  for (int q = 0; q < KT / 32; ++q) {
    short8 af = *(const short8*)&Al[w * 16 + lr][q * 32 + lh * 8];
    #pragma unroll
    for (int nt = 0; nt < 8; ++nt) {
      short8 bf = *(const short8*)(Wbf + (size_t)(nt * 16 + lr) * KT + q * 32 + lh * 8);
      acc[nt] = __builtin_amdgcn_mfma_f32_16x16x32_bf16(af, bf, acc[nt], 0, 0, 0);
    }
  }

  float vb[8], gv[8], bv[8];
  #pragma unroll
  for (int nt = 0; nt < 8; ++nt) {
    int col = nt * 16 + lr;
    vb[nt] = DOBIAS ? bias[col] : 0.f;
    if (DOLN) { gv[nt] = lng[col]; bv[nt] = lnb[col]; }
  }

  #pragma unroll
  for (int r = 0; r < 4; ++r) {
    float vals[8];
    #pragma unroll
    for (int nt = 0; nt < 8; ++nt) vals[nt] = acc[nt][r] + vb[nt];
    if (DOLN) {
      float s1 = 0.f, s2 = 0.f;
      #pragma unroll
      for (int nt = 0; nt < 8; ++nt) { s1 += vals[nt]; s2 += vals[nt] * vals[nt]; }
      #pragma unroll
      for (int m = 1; m < 16; m <<= 1) { s1 += __shfl_xor(s1, m, 64); s2 += __shfl_xor(s2, m, 64); }
      float mu = s1 * (1.0f / 128.0f);
      float var = s2 * (1.0f / 128.0f) - mu * mu;
      float rs = rsqrtf(var + 1e-5f);
      #pragma unroll
      for (int nt = 0; nt < 8; ++nt) vals[nt] = (vals[nt] - mu) * rs * gv[nt] + bv[nt];
    }
    if (DOSILU) {
      #pragma unroll
      for (int nt = 0; nt < 8; ++nt) vals[nt] = silu_f(vals[nt]);
    }
    int row = n0 + w * 16 + lh * 4 + r;
    if (row < n) {
      float* cr = C + (size_t)row * HID;
      #pragma unroll
      for (int nt = 0; nt < 8; ++nt) {
        int col = nt * 16 + lr;
        float o = vals[nt];
        if (DORES) o += R[(size_t)row * HID + col];
        cr[col] = o;
      }
    }
  }
}

// ---------------- fused LN + dual GEMM (natural-layout Pa/Pb) ----------------
// hn = LN(h); Pa = hn@Wa^T + b1; Pb = hn@Wb^T
__global__ __launch_bounds__(256) void pab_ln(
    const float* __restrict__ Hraw, const ushort* __restrict__ Wab,
    const float* __restrict__ lg, const float* __restrict__ lbp,
    const float* __restrict__ eb1,
    float* __restrict__ Hn, float* __restrict__ Pa, float* __restrict__ Pb, int n)
{
  __shared__ float Hs[64][132];
  __shared__ ushort Al[64][136];
  const int tid = threadIdx.x;
  const int n0 = blockIdx.x * 64;

  #pragma unroll
  for (int i = 0; i < 8; ++i) {
    int s = tid + i * 256;
    int row = s >> 5, c4 = (s & 31) * 4;
    int gr = n0 + row;
    float4 v = make_float4(0.f, 0.f, 0.f, 0.f);
    if (gr < n) v = *(const float4*)(Hraw + (size_t)gr * HID + c4);
    *(float4*)&Hs[row][c4] = v;
  }
  __syncthreads();

  const int w = tid >> 6, l = tid & 63;
  const int lr = l & 15, lh = l >> 4;

  {
    const int row = w * 16 + lr;
    float s1 = 0.f, s2 = 0.f;
    #pragma unroll
    for (int j = 0; j < 8; ++j) {
      float4 v = *(float4*)&Hs[row][lh * 32 + j * 4];
      s1 += v.x + v.y + v.z + v.w;
      s2 += v.x * v.x + v.y * v.y + v.z * v.z + v.w * v.w;
    }
    s1 += __shfl_xor(s1, 16, 64); s1 += __shfl_xor(s1, 32, 64);
    s2 += __shfl_xor(s2, 16, 64); s2 += __shfl_xor(s2, 32, 64);
    float mu = s1 * (1.0f / 128.0f);
    float var = s2 * (1.0f / 128.0f) - mu * mu;
    float rs = rsqrtf(var + 1e-5f);
    int gr = n0 + row;
    #pragma unroll
    for (int j = 0; j < 8; ++j) {
      int c = lh * 32 + j * 4;
      float4 v = *(float4*)&Hs[row][c];
      float4 o;
      o.x = (v.x - mu) * rs * lg[c + 0] + lbp[c + 0];
      o.y = (v.y - mu) * rs * lg[c + 1] + lbp[c + 1];
      o.z = (v.z - mu) * rs * lg[c + 2] + lbp[c + 2];
      o.w = (v.w - mu) * rs * lg[c + 3] + lbp[c + 3];
      if (gr < n) *(float4*)(Hn + (size_t)gr * HID + c) = o;
      uint2 p;
      p.x = (uint)f2bf(o.x) | ((uint)f2bf(o.y) << 16);
      p.y = (uint)f2bf(o.z) | ((uint)f2bf(o.w) << 16);
      *(uint2*)&Al[row][c] = p;
    }
  }
  __syncthreads();

  f32x4 zf = {0.f, 0.f, 0.f, 0.f};
  f32x4 acc[16];
  #pragma unroll
  for (int nt = 0; nt < 16; ++nt) acc[nt] = zf;

  #pragma unroll
  for (int q = 0; q < 4; ++q) {
    short8 af = *(const short8*)&Al[w * 16 + lr][q * 32 + lh * 8];
    #pragma unroll
    for (int nt = 0; nt < 16; ++nt) {
      short8 bf = *(const short8*)(Wab + (size_t)(nt * 16 + lr) * HID + q * 32 + lh * 8);
      acc[nt] = __builtin_amdgcn_mfma_f32_16x16x32_bf16(af, bf, acc[nt], 0, 0, 0);
    }
  }

  float be[8];
  #pragma unroll
  for (int nt = 0; nt < 8; ++nt) be[nt] = eb1[nt * 16 + lr];

  #pragma unroll
  for (int r = 0; r < 4; ++r) {
    int row = n0 + w * 16 + lh * 4 + r;
    if (row >= n) break;
    float* pa = Pa + (size_t)row * HID;
    float* pb = Pb + (size_t)row * HID;
    #pragma unroll
    for (int nt = 0; nt < 8; ++nt) {
      int col = nt * 16 + lr;
      pa[col] = acc[nt][r] + be[nt];
      pb[col] = acc[nt + 8][r];
    }
  }
}

// ---------------- per-node CSR edge kernel: one wave = one src node, no atomics ----------------
// S[n] = sum_{e in CSR run of n} SiLU(LN(Pa[n] + Pb[dst_e] + ea_e @ W1c^T))
__global__ __launch_bounds__(256) void node_edge(
    const float* __restrict__ Pa, const float* __restrict__ Pb,
    const ushort* __restrict__ ea_bf,
    const int* __restrict__ dst_s,
    const int* __restrict__ ebase, const int* __restrict__ deg,
    const float* __restrict__ w1c,      // ew1 layer base: rows [c][272], cols 256..271
    const float* __restrict__ elg, const float* __restrict__ elb,
    float* __restrict__ S, int n)
{
  const int tid = threadIdx.x;
  const int wv = __builtin_amdgcn_readfirstlane(tid >> 6);
  const int lane = tid & 63;
  const int node = blockIdx.x * 4 + wv;
  if (node >= n) return;
  const int c0 = lane * 2;

  // per-lane W1c rows (fp32, from original ew1)
  float w10[16], w11[16];
  {
    const float* wr0 = w1c + (size_t)c0 * 272 + 256;
    const float* wr1 = wr0 + 272;
    #pragma unroll
    for (int q = 0; q < 4; ++q) {
      float4 a = *(const float4*)(wr0 + q * 4);
      float4 b = *(const float4*)(wr1 + q * 4);
      w10[q * 4 + 0] = a.x; w10[q * 4 + 1] = a.y; w10[q * 4 + 2] = a.z; w10[q * 4 + 3] = a.w;
      w11[q * 4 + 0] = b.x; w11[q * 4 + 1] = b.y; w11[q * 4 + 2] = b.z; w11[q * 4 + 3] = b.w;
    }
  }
  const float g0 = elg[c0], g1 = elg[c0 + 1];
  const float b0 = elb[c0], b1 = elb[c0 + 1];
  const float pax = Pa[(size_t)node * HID + c0];
  const float pay = Pa[(size_t)node * HID + c0 + 1];

  const int beg = ebase[node];
  const int dg  = deg[node];

  float a0 = 0.f, a1 = 0.f;

  uint4 eaA = {0, 0, 0, 0}, eaB = {0, 0, 0, 0};
  float2 pbc = make_float2(0.f, 0.f);
  if (dg > 0) {
    int eu = __builtin_amdgcn_readfirstlane(beg);
    int d  = __builtin_amdgcn_readfirstlane(dst_s[eu]);
    eaA = *(const uint4*)(ea_bf + (size_t)eu * 16);
    eaB = *(const uint4*)(ea_bf + (size_t)eu * 16 + 8);
    pbc = *(const float2*)(Pb + (size_t)d * HID + c0);
  }

  for (int i = 0; i < dg; ++i) {
    // prefetch edge i+1
    uint4 eaA_n = {0, 0, 0, 0}, eaB_n = {0, 0, 0, 0};
    float2 pbn = make_float2(0.f, 0.f);
    if (i + 1 < dg) {
      int eu = __builtin_amdgcn_readfirstlane(beg + i + 1);
      int d  = __builtin_amdgcn_readfirstlane(dst_s[eu]);
      eaA_n = *(const uint4*)(ea_bf + (size_t)eu * 16);
      eaB_n = *(const uint4*)(ea_bf + (size_t)eu * 16 + 8);
      pbn = *(const float2*)(Pb + (size_t)d * HID + c0);
    }

    // unpack ea (bf16 pairs -> f32)
    float ev[16];
    uint u;
    u = eaA.x; ev[0]  = __uint_as_float(u << 16); ev[1]  = __uint_as_float(u & 0xffff0000u);
    u = eaA.y; ev[2]  = __uint_as_float(u << 16); ev[3]  = __uint_as_float(u & 0xffff0000u);
    u = eaA.z; ev[4]  = __uint_as_float(u << 16); ev[5]  = __uint_as_float(u & 0xffff0000u);
    u = eaA.w; ev[6]  = __uint_as_float(u << 16); ev[7]  = __uint_as_float(u & 0xffff0000u);
    u = eaB.x; ev[8]  = __uint_as_float(u << 16); ev[9]  = __uint_as_float(u & 0xffff0000u);
    u = eaB.y; ev[10] = __uint_as_float(u << 16); ev[11] = __uint_as_float(u & 0xffff0000u);
    u = eaB.z; ev[12] = __uint_as_float(u << 16); ev[13] = __uint_as_float(u & 0xffff0000u);
    u = eaB.w; ev[14] = __uint_as_float(u << 16); ev[15] = __uint_as_float(u & 0xffff0000u);

    float x0 = pax + pbc.x;
    float x1 = pay + pbc.y;
    #pragma unroll
    for (int k = 0; k < 16; ++k) {
      x0 = fmaf(ev[k], w10[k], x0);
      x1 = fmaf(ev[k], w11[k], x1);
    }

    float s1 = x0 + x1, s2 = x0 * x0 + x1 * x1;
    #pragma unroll
    for (int m = 1; m < 64; m <<= 1) {
      s1 += __shfl_xor(s1, m, 64);
      s2 += __shfl_xor(s2, m, 64);
    }
    float mu = s1 * (1.0f / 128.0f);
    float var = s2 * (1.0f / 128.0f) - mu * mu;
    float rs = rsqrtf(var + 1e-5f);
    a0 += silu_f((x0 - mu) * rs * g0 + b0);
    a1 += silu_f((x1 - mu) * rs * g1 + b1);

    eaA = eaA_n; eaB = eaB_n; pbc = pbn;
  }

  *(float2*)(S + (size_t)node * HID + c0) = make_float2(a0, a1);
}

// ---------------- node MLP part 1 (folded): tmp = SiLU(LN(hn@N1a^T + Shi@W2N^T + Slo@W2N^T + deg*nv + nb1)) ----------------
__global__ __launch_bounds__(256) void node1_gemm(
    const float* __restrict__ Hn, const float* __restrict__ S,
    const ushort* __restrict__ N1a, const ushort* __restrict__ W2N,
    const float* __restrict__ nb1, const float* __restrict__ nv,
    const int* __restrict__ deg,
    const float* __restrict__ lng, const float* __restrict__ lnb,
    float* __restrict__ C, int n)
{
  __shared__ ushort Ahn[64][136];
  __shared__ ushort Ah[64][136];
  __shared__ ushort Alo[64][136];
  const int tid = threadIdx.x;
  const int n0 = blockIdx.x * 64;

  #pragma unroll
  for (int i = 0; i < 8; ++i) {
    int s = tid + i * 256;
    int row = s >> 5, c4 = (s & 31) * 4;
    int gr = n0 + row;
    float4 vh = make_float4(0.f, 0.f, 0.f, 0.f);
    float4 vs = make_float4(0.f, 0.f, 0.f, 0.f);
    if (gr < n) {
      vh = *(const float4*)(Hn + (size_t)gr * HID + c4);
      vs = *(const float4*)(S + (size_t)gr * HID + c4);
    }
    uint2 ph;
    ph.x = (uint)f2bf(vh.x) | ((uint)f2bf(vh.y) << 16);
    ph.y = (uint)f2bf(vh.z) | ((uint)f2bf(vh.w) << 16);
    *(uint2*)&Ahn[row][c4] = ph;
    ushort hx = f2bf(vs.x), hy = f2bf(vs.y), hz = f2bf(vs.z), hw = f2bf(vs.w);
    uint2 ps, pl;
    ps.x = (uint)hx | ((uint)hy << 16);
    ps.y = (uint)hz | ((uint)hw << 16);
    pl.x = (uint)f2bf(vs.x - bf2f(hx)) | ((uint)f2bf(vs.y - bf2f(hy)) << 16);
    pl.y = (uint)f2bf(vs.z - bf2f(hz)) | ((uint)f2bf(vs.w - bf2f(hw)) << 16);
    *(uint2*)&Ah[row][c4]  = ps;
    *(uint2*)&Alo[row][c4] = pl;
  }
  __syncthreads();

  const int w = tid >> 6, l = tid & 63;
  const int lr = l & 15, lh = l >> 4;

  f32x4 zf = {0.f, 0.f, 0.f, 0.f};
  f32x4 acc[8];
  #pragma unroll
  for (int nt = 0; nt < 8; ++nt) acc[nt] = zf;

  #pragma unroll
  for (int q = 0; q < 4; ++q) {
    short8 an = *(const short8*)&Ahn[w * 16 + lr][q * 32 + lh * 8];
    short8 ah = *(const short8*)&Ah[w * 16 + lr][q * 32 + lh * 8];
    short8 al = *(const short8*)&Alo[w * 16 + lr][q * 32 + lh * 8];
    #pragma unroll
    for (int nt = 0; nt < 8; ++nt) {
      short8 b1f = *(const short8*)(N1a + (size_t)(nt * 16 + lr) * HID + q * 32 + lh * 8);
      short8 b2f = *(const short8*)(W2N + (size_t)(nt * 16 + lr) * HID + q * 32 + lh * 8);
      acc[nt] = __builtin_amdgcn_mfma_f32_16x16x32_bf16(an, b1f, acc[nt], 0, 0, 0);
      acc[nt] = __builtin_amdgcn_mfma_f32_16x16x32_bf16(ah, b2f, acc[nt], 0, 0, 0);
      acc[nt] = __builtin_amdgcn_mfma_f32_16x16x32_bf16(al, b2f, acc[nt], 0, 0, 0);
    }
  }

  float vb[8], vn[8], gv[8], bv[8];
  #pragma unroll
  for (int nt = 0; nt < 8; ++nt) {
    int col = nt * 16 + lr;
    vb[nt] = nb1[col]; vn[nt] = nv[col];
    gv[nt] = lng[col]; bv[nt] = lnb[col];
  }

  #pragma unroll
  for (int r = 0; r < 4; ++r) {
    int row = n0 + w * 16 + lh * 4 + r;
    float degf = (row < n) ? (float)deg[row] : 0.f;
    float vals[8];
    #pragma unroll
    for (int nt = 0; nt < 8; ++nt) vals[nt] = acc[nt][r] + vb[nt] + degf * vn[nt];
    float s1 = 0.f, s2 = 0.f;
    #pragma unroll
    for (int nt = 0; nt < 8; ++nt) { s1 += vals[nt]; s2 += vals[nt] * vals[nt]; }
    #pragma unroll
    for (int m = 1; m < 16; m <<= 1) { s1 += __shfl_xor(s1, m, 64); s2 += __shfl_xor(s2, m, 64); }
    float mu = s1 * (1.0f / 128.0f);
    float var = s2 * (1.0f / 128.0f) - mu * mu;
    float rs = rsqrtf(var + 1e-5f);
    if (row < n) {
      float* cr = C + (size_t)row * HID;
      #pragma unroll
      for (int nt = 0; nt < 8; ++nt) {
        int col = nt * 16 + lr;
        cr[col] = silu_f((vals[nt] - mu) * rs * gv[nt] + bv[nt]);
      }
    }
  }
}

extern "C" void kernel_launch(void* const* d_in, const int* in_sizes, int n_in,
                              void* d_out, int out_size, void* d_ws, size_t ws_size,
                              hipStream_t stream)
{
  const float* in_h  = (const float*)d_in[0];
  const int*   edges = (const int*)d_in[1];
  const float* ea    = (const float*)d_in[2];
  const float* ei_w1 = (const float*)d_in[3];
  const float* ei_b1 = (const float*)d_in[4];
  const float* ei_w2 = (const float*)d_in[5];
  const float* ei_b2 = (const float*)d_in[6];
  const float* ng    = (const float*)d_in[7];
  const float* nbp   = (const float*)d_in[8];
  const float* ew1   = (const float*)d_in[9];
  const float* eb1   = (const float*)d_in[10];
  const float* elg   = (const float*)d_in[11];
  const float* elb   = (const float*)d_in[12];
  const float* ew2   = (const float*)d_in[13];
  const float* eb2   = (const float*)d_in[14];
  const float* nw1   = (const float*)d_in[15];
  const float* nb1   = (const float*)d_in[16];
  const float* nlg   = (const float*)d_in[17];
  const float* nlb   = (const float*)d_in[18];
  const float* nw2   = (const float*)d_in[19];
  const float* nb2   = (const float*)d_in[20];
  const float* eo_w1 = (const float*)d_in[21];
  const float* eo_b1 = (const float*)d_in[22];
  const float* eo_w2 = (const float*)d_in[23];
  const float* eo_b2 = (const float*)d_in[24];

  float* wf    = (float*)d_ws;
  float* B_h   = wf;
  float* B_hn  = wf + NNH;
  float* B_S   = wf + 2 * NNH;   // S (edge-sum); perm alias during setup
  float* B_tmp = wf + 3 * NNH;   // Pa / MLP intermediate
  float* B_pb  = wf + 4 * NNH;   // Pb

  const size_t WOFF = 5 * NNH;
  ushort* wu = (ushort*)(wf + WOFF);
  // ei1@0, ei2@16384, eo1@32768, eo2@49152; per-layer base 65536 + l*104448:
  //   Wab@0 [256][128] | W2N@32768 | N1a@49152 | N2@81920
  const size_t SOFF = WOFF + 262144;
  int* dst_s = (int*)(wf + SOFF);
  int* cnt   = dst_s + NE;       // = deg
  int* cur   = cnt + NPAD;
  int* base  = cur + NPAD;
  ushort* ea_s = (ushort*)(base + NPAD);
  float* nvb = (float*)(ea_s + (size_t)NE * 16);   // 4*128 fp32
  int* perm  = (int*)B_S;

  const int NB  = (NN + 63) / 64;
  const int NBE = (NN + 3) / 4;     // node_edge blocks (4 waves = 4 nodes each)
  const int NEB = (NE + 255) / 256;

  const int* erow = edges;
  const int* ecol = edges + NE;

  // ---- counting sort by src (once) ----
  zero_i<<<(2 * NPAD + 255) / 256, 256, 0, stream>>>(cnt, 2 * NPAD);
  count_src<<<NEB, 256, 0, stream>>>(erow, cnt);
  scan_excl<<<1, 1024, 0, stream>>>(cnt, base, NN);
  place_edges<<<NEB, 256, 0, stream>>>(erow, ecol, base, cur, dst_s, perm);
  permute_ea_bf<<<(NE * 4 + 255) / 256, 256, 0, stream>>>((const float4*)ea, perm, ea_s);

  // ---- weight conversion / folding ----
  cvt4<<<256, 256, 0, stream>>>(ei_w1, ei_w2, eo_w1, eo_w2, wu);
  cvt_wab<<<512, 256, 0, stream>>>(ew1, wu + 65536);
  cvt_std<<<(4 * 16384 + 255) / 256, 256, 0, stream>>>(nw2, wu + 65536 + 81920, 128, 128, 16384);
  fold_w<<<512, 128, 0, stream>>>(nw1, ew2, eb2, wu + 65536, nvb);

  // ---- embedding_in ----
  mgemm<128, true, false, true,  false><<<NB, 256, 0, stream>>>(in_h, nullptr, wu, ei_b1, nullptr, nullptr, nullptr, B_tmp, NN);
  mgemm<128, true, false, false, false><<<NB, 256, 0, stream>>>(B_tmp, nullptr, wu + 16384, ei_b2, nullptr, nullptr, nullptr, B_h, NN);

  for (int lyr = 0; lyr < 4; ++lyr) {
    ushort* lb = wu + 65536 + lyr * 104448;
    pab_ln<<<NB, 256, 0, stream>>>(B_h, lb, ng + 128 * lyr, nbp + 128 * lyr,
        eb1 + 128 * lyr, B_hn, B_tmp, B_pb, NN);
    node_edge<<<NBE, 256, 0, stream>>>(B_tmp, B_pb, ea_s, dst_s, base, cnt,
        ew1 + 34816 * lyr, elg + 128 * lyr, elb + 128 * lyr, B_S, NN);
    node1_gemm<<<NB, 256, 0, stream>>>(B_hn, B_S, lb + 49152, lb + 32768,
        nb1 + 128 * lyr, nvb + 128 * lyr, cnt,
        nlg + 128 * lyr, nlb + 128 * lyr, B_tmp, NN);
    mgemm<128, true, false, false, true ><<<NB, 256, 0, stream>>>(B_tmp, nullptr, lb + 81920, nb2 + 128 * lyr,
        nullptr, nullptr, B_hn, B_h, NN);
  }

  // ---- embedding_out ----
  mgemm<128, true, false, true,  false><<<NB, 256, 0, stream>>>(B_h, nullptr, wu + 32768, eo_b1, nullptr, nullptr, nullptr, B_tmp, NN);
  mgemm<128, true, false, false, false><<<NB, 256, 0, stream>>>(B_tmp, nullptr, wu + 49152, eo_b2, nullptr, nullptr, nullptr, (float*)d_out, NN);
}

// Round 9
// 1423.978 us; speedup vs baseline: 3.1691x; 1.0262x over previous
//
#include <hip/hip_runtime.h>
#include <math.h>

#define NN 50000
#define NE 800000
#define HID 128
#define NNH ((size_t)NN * HID)
#define NPAD 50176

typedef __attribute__((ext_vector_type(8))) short short8;
typedef __attribute__((ext_vector_type(4))) float f32x4;

__device__ __forceinline__ ushort f2bf(float f) {
  unsigned u = __float_as_uint(f);
  unsigned r = (u + 0x7fffu + ((u >> 16) & 1u)) >> 16;
  return (ushort)r;
}
__device__ __forceinline__ float bf2f(ushort h) {
  return __uint_as_float(((unsigned)h) << 16);
}
__device__ __forceinline__ float silu_f(float x) { return x / (1.0f + __expf(-x)); }

// ---------------- utility ----------------
__global__ __launch_bounds__(256) void zero_i(int* __restrict__ p, int n)
{
  int i = blockIdx.x * 256 + threadIdx.x;
  if (i < n) p[i] = 0;
}

// ---------------- counting sort of edges by src ----------------
__global__ __launch_bounds__(256) void count_src(const int* __restrict__ src, int* __restrict__ cnt)
{
  int e = blockIdx.x * 256 + threadIdx.x;
  if (e < NE) atomicAdd(&cnt[src[e]], 1);
}

__global__ __launch_bounds__(1024) void scan_excl(const int* __restrict__ cnt, int* __restrict__ base, int n)
{
  __shared__ int ws[16];
  int t = threadIdx.x;
  const int per = (n + 1023) / 1024;
  int s0 = t * per;
  int sum = 0;
  for (int i = 0; i < per; ++i) { int idx = s0 + i; if (idx < n) sum += cnt[idx]; }
  int lane = t & 63, w = t >> 6;
  int v = sum;
  #pragma unroll
  for (int m = 1; m < 64; m <<= 1) { int o = __shfl_up(v, m, 64); if (lane >= m) v += o; }
  if (lane == 63) ws[w] = v;
  __syncthreads();
  if (t == 0) { int a = 0; for (int i = 0; i < 16; ++i) { int x = ws[i]; ws[i] = a; a += x; } }
  __syncthreads();
  int run = ws[w] + v - sum;
  for (int i = 0; i < per; ++i) {
    int idx = s0 + i;
    if (idx < n) { base[idx] = run; run += cnt[idx]; }
  }
}

__global__ __launch_bounds__(256) void place_edges(const int* __restrict__ src, const int* __restrict__ dst,
    const int* __restrict__ base, int* __restrict__ cur,
    int* __restrict__ dst_s, int* __restrict__ perm)
{
  int e = blockIdx.x * 256 + threadIdx.x;
  if (e >= NE) return;
  int s = src[e];
  int p = base[s] + atomicAdd(&cur[s], 1);
  dst_s[p] = dst[e]; perm[p] = e;
}

__global__ __launch_bounds__(256) void permute_ea_bf(const float4* __restrict__ ea,
    const int* __restrict__ perm, ushort* __restrict__ ea_s)
{
  int i = blockIdx.x * 256 + threadIdx.x;
  if (i >= NE * 4) return;
  int e = i >> 2, q = i & 3;
  float4 v = ea[(size_t)perm[e] * 4 + q];
  uint2 p;
  p.x = (uint)f2bf(v.x) | ((uint)f2bf(v.y) << 16);
  p.y = (uint)f2bf(v.z) | ((uint)f2bf(v.w) << 16);
  *(uint2*)&ea_s[(size_t)e * 16 + q * 4] = p;
}

// ---------------- weight conversion ----------------
__global__ __launch_bounds__(256) void cvt4(const float* __restrict__ s0, const float* __restrict__ s1,
    const float* __restrict__ s2, const float* __restrict__ s3, ushort* __restrict__ d)
{
  int i = blockIdx.x * 256 + threadIdx.x;
  if (i >= 65536) return;
  const float* s = (i < 16384) ? s0 : (i < 32768) ? s1 : (i < 49152) ? s2 : s3;
  d[i] = f2bf(s[i & 16383]);
}
__global__ __launch_bounds__(256) void cvt_wab(const float* __restrict__ s, ushort* __restrict__ d)
{
  int i = blockIdx.x * 256 + threadIdx.x;
  if (i >= 131072) return;
  int l = i >> 15, rem = i & 32767;
  int r = rem >> 7, c = rem & 127;
  int srow = r & 127, scol = ((r >> 7) << 7) + c;
  d[l * 104448 + r * 128 + c] = f2bf(s[(size_t)l * 34816 + srow * 272 + scol]);
}
__global__ __launch_bounds__(256) void cvt_std(const float* __restrict__ s, ushort* __restrict__ d,
    int rows, int cols, int lss)
{
  int i = blockIdx.x * 256 + threadIdx.x;
  int n = 4 * rows * cols;
  if (i >= n) return;
  int rc = rows * cols;
  int l = i / rc, rem = i - l * rc;
  d[l * 104448 + rem] = f2bf(s[(size_t)l * lss + rem]);
}

// ---------------- fold: W2N = N1b @ W2 (bf16), N1a (bf16), nv = N1b @ b2 (fp32) ----------------
__global__ __launch_bounds__(128) void fold_w(const float* __restrict__ nw1,
    const float* __restrict__ ew2, const float* __restrict__ eb2,
    ushort* __restrict__ wu_base, float* __restrict__ nv)
{
  __shared__ float red[2];
  int bid = blockIdx.x;
  int l = bid >> 7, m = bid & 127;
  int j = threadIdx.x;
  const float* n1row = nw1 + (size_t)l * 32768 + (size_t)m * 256;
  const float* n1b = n1row + 128;
  const float* w2 = ew2 + (size_t)l * 16384;
  float s = 0.f;
  for (int k = 0; k < 128; ++k) s = fmaf(n1b[k], w2[k * 128 + j], s);
  ushort* lb = wu_base + (size_t)l * 104448;
  lb[32768 + m * 128 + j] = f2bf(s);          // W2N
  lb[49152 + m * 128 + j] = f2bf(n1row[j]);   // N1a
  float p = n1b[j] * eb2[l * 128 + j];
  #pragma unroll
  for (int mm = 1; mm < 64; mm <<= 1) p += __shfl_xor(p, mm, 64);
  if ((j & 63) == 0) red[j >> 6] = p;
  __syncthreads();
  if (j == 0) nv[l * 128 + m] = red[0] + red[1];
}

// ---------------- fused 2-layer MLP: C = silu(A@W1^T + b1) @ W2^T + b2 ----------------
// Intermediate kept as bf16 in the SAME LDS tile (wave-private rows -> no barrier).
__global__ __launch_bounds__(256) void emb2(
    const float* __restrict__ A,
    const ushort* __restrict__ W1, const float* __restrict__ b1,
    const ushort* __restrict__ W2, const float* __restrict__ b2,
    float* __restrict__ C, int n)
{
  __shared__ ushort Al[64][136];
  const int tid = threadIdx.x;
  const int n0 = blockIdx.x * 64;

  #pragma unroll
  for (int i = 0; i < 8; ++i) {
    int s = tid + i * 256;
    int row = s >> 5, c4 = (s & 31) * 4;
    int gr = n0 + row;
    float4 v = make_float4(0.f, 0.f, 0.f, 0.f);
    if (gr < n) v = *(const float4*)(A + (size_t)gr * HID + c4);
    uint2 p;
    p.x = (uint)f2bf(v.x) | ((uint)f2bf(v.y) << 16);
    p.y = (uint)f2bf(v.z) | ((uint)f2bf(v.w) << 16);
    *(uint2*)&Al[row][c4] = p;
  }
  __syncthreads();

  const int w = tid >> 6, l = tid & 63;
  const int lr = l & 15, lh = l >> 4;

  f32x4 zf = {0.f, 0.f, 0.f, 0.f};
  f32x4 acc[8];
  #pragma unroll
  for (int nt = 0; nt < 8; ++nt) acc[nt] = zf;

  #pragma unroll
  for (int q = 0; q < 4; ++q) {
    short8 af = *(const short8*)&Al[w * 16 + lr][q * 32 + lh * 8];
    #pragma unroll
    for (int nt = 0; nt < 8; ++nt) {
      short8 bf = *(const short8*)(W1 + (size_t)(nt * 16 + lr) * HID + q * 32 + lh * 8);
      acc[nt] = __builtin_amdgcn_mfma_f32_16x16x32_bf16(af, bf, acc[nt], 0, 0, 0);
    }
  }

  float vb[8];
  #pragma unroll
  for (int nt = 0; nt < 8; ++nt) vb[nt] = b1[nt * 16 + lr];

  // silu -> bf16 back into own wave's rows of Al (no barrier needed)
  #pragma unroll
  for (int r = 0; r < 4; ++r) {
    int row = w * 16 + lh * 4 + r;
    #pragma unroll
    for (int nt = 0; nt < 8; ++nt)
      Al[row][nt * 16 + lr] = f2bf(silu_f(acc[nt][r] + vb[nt]));
  }

  f32x4 acc2[8];
  #pragma unroll
  for (int nt = 0; nt < 8; ++nt) acc2[nt] = zf;
  #pragma unroll
  for (int q = 0; q < 4; ++q) {
    short8 af = *(const short8*)&Al[w * 16 + lr][q * 32 + lh * 8];
    #pragma unroll
    for (int nt = 0; nt < 8; ++nt) {
      short8 bf = *(const short8*)(W2 + (size_t)(nt * 16 + lr) * HID + q * 32 + lh * 8);
      acc2[nt] = __builtin_amdgcn_mfma_f32_16x16x32_bf16(af, bf, acc2[nt], 0, 0, 0);
    }
  }

  float vb2[8];
  #pragma unroll
  for (int nt = 0; nt < 8; ++nt) vb2[nt] = b2[nt * 16 + lr];
  #pragma unroll
  for (int r = 0; r < 4; ++r) {
    int row = n0 + w * 16 + lh * 4 + r;
    if (row < n) {
      float* cr = C + (size_t)row * HID;
      #pragma unroll
      for (int nt = 0; nt < 8; ++nt)
        cr[nt * 16 + lr] = acc2[nt][r] + vb2[nt];
    }
  }
}

// ---------------- fused LN + dual GEMM (natural-layout Pa/Pb) ----------------
__global__ __launch_bounds__(256) void pab_ln(
    const float* __restrict__ Hraw, const ushort* __restrict__ Wab,
    const float* __restrict__ lg, const float* __restrict__ lbp,
    const float* __restrict__ eb1,
    float* __restrict__ Hn, float* __restrict__ Pa, float* __restrict__ Pb, int n)
{
  __shared__ float Hs[64][132];
  __shared__ ushort Al[64][136];
  const int tid = threadIdx.x;
  const int n0 = blockIdx.x * 64;

  #pragma unroll
  for (int i = 0; i < 8; ++i) {
    int s = tid + i * 256;
    int row = s >> 5, c4 = (s & 31) * 4;
    int gr = n0 + row;
    float4 v = make_float4(0.f, 0.f, 0.f, 0.f);
    if (gr < n) v = *(const float4*)(Hraw + (size_t)gr * HID + c4);
    *(float4*)&Hs[row][c4] = v;
  }
  __syncthreads();

  const int w = tid >> 6, l = tid & 63;
  const int lr = l & 15, lh = l >> 4;

  {
    const int row = w * 16 + lr;
    float s1 = 0.f, s2 = 0.f;
    #pragma unroll
    for (int j = 0; j < 8; ++j) {
      float4 v = *(float4*)&Hs[row][lh * 32 + j * 4];
      s1 += v.x + v.y + v.z + v.w;
      s2 += v.x * v.x + v.y * v.y + v.z * v.z + v.w * v.w;
    }
    s1 += __shfl_xor(s1, 16, 64); s1 += __shfl_xor(s1, 32, 64);
    s2 += __shfl_xor(s2, 16, 64); s2 += __shfl_xor(s2, 32, 64);
    float mu = s1 * (1.0f / 128.0f);
    float var = s2 * (1.0f / 128.0f) - mu * mu;
    float rs = rsqrtf(var + 1e-5f);
    int gr = n0 + row;
    #pragma unroll
    for (int j = 0; j < 8; ++j) {
      int c = lh * 32 + j * 4;
      float4 v = *(float4*)&Hs[row][c];
      float4 o;
      o.x = (v.x - mu) * rs * lg[c + 0] + lbp[c + 0];
      o.y = (v.y - mu) * rs * lg[c + 1] + lbp[c + 1];
      o.z = (v.z - mu) * rs * lg[c + 2] + lbp[c + 2];
      o.w = (v.w - mu) * rs * lg[c + 3] + lbp[c + 3];
      if (gr < n) *(float4*)(Hn + (size_t)gr * HID + c) = o;
      uint2 p;
      p.x = (uint)f2bf(o.x) | ((uint)f2bf(o.y) << 16);
      p.y = (uint)f2bf(o.z) | ((uint)f2bf(o.w) << 16);
      *(uint2*)&Al[row][c] = p;
    }
  }
  __syncthreads();

  f32x4 zf = {0.f, 0.f, 0.f, 0.f};
  f32x4 acc[16];
  #pragma unroll
  for (int nt = 0; nt < 16; ++nt) acc[nt] = zf;

  #pragma unroll
  for (int q = 0; q < 4; ++q) {
    short8 af = *(const short8*)&Al[w * 16 + lr][q * 32 + lh * 8];
    #pragma unroll
    for (int nt = 0; nt < 16; ++nt) {
      short8 bf = *(const short8*)(Wab + (size_t)(nt * 16 + lr) * HID + q * 32 + lh * 8);
      acc[nt] = __builtin_amdgcn_mfma_f32_16x16x32_bf16(af, bf, acc[nt], 0, 0, 0);
    }
  }

  float be[8];
  #pragma unroll
  for (int nt = 0; nt < 8; ++nt) be[nt] = eb1[nt * 16 + lr];

  #pragma unroll
  for (int r = 0; r < 4; ++r) {
    int row = n0 + w * 16 + lh * 4 + r;
    if (row >= n) break;
    float* pa = Pa + (size_t)row * HID;
    float* pb = Pb + (size_t)row * HID;
    #pragma unroll
    for (int nt = 0; nt < 8; ++nt) {
      int col = nt * 16 + lr;
      pa[col] = acc[nt][r] + be[nt];
      pb[col] = acc[nt + 8][r];
    }
  }
}

// ---------------- per-node CSR edge kernel: one wave = one src node, 2 edges/iter, no atomics ----------------
__global__ __launch_bounds__(256) void node_edge(
    const float* __restrict__ Pa, const float* __restrict__ Pb,
    const ushort* __restrict__ ea_bf,
    const int* __restrict__ dst_s,
    const int* __restrict__ ebase, const int* __restrict__ deg,
    const float* __restrict__ w1c,
    const float* __restrict__ elg, const float* __restrict__ elb,
    float* __restrict__ S, int n)
{
  const int tid = threadIdx.x;
  const int wv = __builtin_amdgcn_readfirstlane(tid >> 6);
  const int lane = tid & 63;
  const int node = blockIdx.x * 4 + wv;
  if (node >= n) return;
  const int c0 = lane * 2;

  float w10[16], w11[16];
  {
    const float* wr0 = w1c + (size_t)c0 * 272 + 256;
    const float* wr1 = wr0 + 272;
    #pragma unroll
    for (int q = 0; q < 4; ++q) {
      float4 a = *(const float4*)(wr0 + q * 4);
      float4 b = *(const float4*)(wr1 + q * 4);
      w10[q * 4 + 0] = a.x; w10[q * 4 + 1] = a.y; w10[q * 4 + 2] = a.z; w10[q * 4 + 3] = a.w;
      w11[q * 4 + 0] = b.x; w11[q * 4 + 1] = b.y; w11[q * 4 + 2] = b.z; w11[q * 4 + 3] = b.w;
    }
  }
  const float g0 = elg[c0], g1 = elg[c0 + 1];
  const float b0 = elb[c0], b1 = elb[c0 + 1];
  const float pax = Pa[(size_t)node * HID + c0];
  const float pay = Pa[(size_t)node * HID + c0 + 1];

  const int beg = __builtin_amdgcn_readfirstlane(ebase[node]);
  const int dg  = __builtin_amdgcn_readfirstlane(deg[node]);

  float a0 = 0.f, a1 = 0.f;

  uint4 eA0 = make_uint4(0,0,0,0), eB0 = eA0, eA1 = eA0, eB1 = eA0;
  float2 p0 = make_float2(0.f, 0.f), p1 = p0;

  auto LOADE = [&](int idx, uint4& ea, uint4& eb, float2& pb) {
    int eu = __builtin_amdgcn_readfirstlane(beg + idx);
    int d  = dst_s[eu];
    ea = *(const uint4*)(ea_bf + (size_t)eu * 16);
    eb = *(const uint4*)(ea_bf + (size_t)eu * 16 + 8);
    pb = *(const float2*)(Pb + (size_t)d * HID + c0);
  };
  auto PROCESS = [&](const uint4& eaA, const uint4& eaB, const float2& pbc) {
    float ev[16];
    uint u;
    u = eaA.x; ev[0]  = __uint_as_float(u << 16); ev[1]  = __uint_as_float(u & 0xffff0000u);
    u = eaA.y; ev[2]  = __uint_as_float(u << 16); ev[3]  = __uint_as_float(u & 0xffff0000u);
    u = eaA.z; ev[4]  = __uint_as_float(u << 16); ev[5]  = __uint_as_float(u & 0xffff0000u);
    u = eaA.w; ev[6]  = __uint_as_float(u << 16); ev[7]  = __uint_as_float(u & 0xffff0000u);
    u = eaB.x; ev[8]  = __uint_as_float(u << 16); ev[9]  = __uint_as_float(u & 0xffff0000u);
    u = eaB.y; ev[10] = __uint_as_float(u << 16); ev[11] = __uint_as_float(u & 0xffff0000u);
    u = eaB.z; ev[12] = __uint_as_float(u << 16); ev[13] = __uint_as_float(u & 0xffff0000u);
    u = eaB.w; ev[14] = __uint_as_float(u << 16); ev[15] = __uint_as_float(u & 0xffff0000u);

    float x0 = pax + pbc.x;
    float x1 = pay + pbc.y;
    #pragma unroll
    for (int k = 0; k < 16; ++k) {
      x0 = fmaf(ev[k], w10[k], x0);
      x1 = fmaf(ev[k], w11[k], x1);
    }
    float s1 = x0 + x1, s2 = x0 * x0 + x1 * x1;
    #pragma unroll
    for (int m = 1; m < 64; m <<= 1) {
      s1 += __shfl_xor(s1, m, 64);
      s2 += __shfl_xor(s2, m, 64);
    }
    float mu = s1 * (1.0f / 128.0f);
    float var = s2 * (1.0f / 128.0f) - mu * mu;
    float rs = rsqrtf(var + 1e-5f);
    a0 += silu_f((x0 - mu) * rs * g0 + b0);
    a1 += silu_f((x1 - mu) * rs * g1 + b1);
  };

  if (dg > 0) LOADE(0, eA0, eB0, p0);
  if (dg > 1) LOADE(1, eA1, eB1, p1);

  for (int i = 0; i < dg; i += 2) {
    uint4 nA0 = make_uint4(0,0,0,0), nB0 = nA0, nA1 = nA0, nB1 = nA0;
    float2 np0 = make_float2(0.f, 0.f), np1 = np0;
    if (i + 2 < dg) LOADE(i + 2, nA0, nB0, np0);
    if (i + 3 < dg) LOADE(i + 3, nA1, nB1, np1);

    PROCESS(eA0, eB0, p0);
    if (i + 1 < dg) PROCESS(eA1, eB1, p1);

    eA0 = nA0; eB0 = nB0; p0 = np0;
    eA1 = nA1; eB1 = nB1; p1 = np1;
  }

  *(float2*)(S + (size_t)node * HID + c0) = make_float2(a0, a1);
}

// ---------------- fused node MLP: h' = hn + (silu(LN(hn@N1a^T + S@W2N^T + deg*nv + nb1)))@N2^T + nb2 ----------------
// S consumed via hi/lo bf16 split; intermediate bf16 written in place into Ahn tile (wave-private rows).
__global__ __launch_bounds__(256) void node_mlp(
    const float* __restrict__ Hn, const float* __restrict__ S,
    const ushort* __restrict__ N1a, const ushort* __restrict__ W2N, const ushort* __restrict__ N2,
    const float* __restrict__ nb1, const float* __restrict__ nv, const int* __restrict__ deg,
    const float* __restrict__ lng, const float* __restrict__ lnb, const float* __restrict__ nb2,
    float* __restrict__ C, int n)
{
  __shared__ ushort Ahn[64][136];
  __shared__ ushort Ah[64][136];
  __shared__ ushort Alo[64][136];
  const int tid = threadIdx.x;
  const int n0 = blockIdx.x * 64;

  #pragma unroll
  for (int i = 0; i < 8; ++i) {
    int s = tid + i * 256;
    int row = s >> 5, c4 = (s & 31) * 4;
    int gr = n0 + row;
    float4 vh = make_float4(0.f, 0.f, 0.f, 0.f);
    float4 vs = make_float4(0.f, 0.f, 0.f, 0.f);
    if (gr < n) {
      vh = *(const float4*)(Hn + (size_t)gr * HID + c4);
      vs = *(const float4*)(S + (size_t)gr * HID + c4);
    }
    uint2 ph;
    ph.x = (uint)f2bf(vh.x) | ((uint)f2bf(vh.y) << 16);
    ph.y = (uint)f2bf(vh.z) | ((uint)f2bf(vh.w) << 16);
    *(uint2*)&Ahn[row][c4] = ph;
    ushort hx = f2bf(vs.x), hy = f2bf(vs.y), hz = f2bf(vs.z), hw = f2bf(vs.w);
    uint2 ps, pl;
    ps.x = (uint)hx | ((uint)hy << 16);
    ps.y = (uint)hz | ((uint)hw << 16);
    pl.x = (uint)f2bf(vs.x - bf2f(hx)) | ((uint)f2bf(vs.y - bf2f(hy)) << 16);
    pl.y = (uint)f2bf(vs.z - bf2f(hz)) | ((uint)f2bf(vs.w - bf2f(hw)) << 16);
    *(uint2*)&Ah[row][c4]  = ps;
    *(uint2*)&Alo[row][c4] = pl;
  }
  __syncthreads();

  const int w = tid >> 6, l = tid & 63;
  const int lr = l & 15, lh = l >> 4;

  f32x4 zf = {0.f, 0.f, 0.f, 0.f};
  f32x4 acc[8];
  #pragma unroll
  for (int nt = 0; nt < 8; ++nt) acc[nt] = zf;

  #pragma unroll
  for (int q = 0; q < 4; ++q) {
    short8 an = *(const short8*)&Ahn[w * 16 + lr][q * 32 + lh * 8];
    short8 ah = *(const short8*)&Ah[w * 16 + lr][q * 32 + lh * 8];
    short8 al = *(const short8*)&Alo[w * 16 + lr][q * 32 + lh * 8];
    #pragma unroll
    for (int nt = 0; nt < 8; ++nt) {
      short8 b1f = *(const short8*)(N1a + (size_t)(nt * 16 + lr) * HID + q * 32 + lh * 8);
      short8 b2f = *(const short8*)(W2N + (size_t)(nt * 16 + lr) * HID + q * 32 + lh * 8);
      acc[nt] = __builtin_amdgcn_mfma_f32_16x16x32_bf16(an, b1f, acc[nt], 0, 0, 0);
      acc[nt] = __builtin_amdgcn_mfma_f32_16x16x32_bf16(ah, b2f, acc[nt], 0, 0, 0);
      acc[nt] = __builtin_amdgcn_mfma_f32_16x16x32_bf16(al, b2f, acc[nt], 0, 0, 0);
    }
  }

  float vb[8], vn[8], gv[8], bv[8];
  #pragma unroll
  for (int nt = 0; nt < 8; ++nt) {
    int col = nt * 16 + lr;
    vb[nt] = nb1[col]; vn[nt] = nv[col];
    gv[nt] = lng[col]; bv[nt] = lnb[col];
  }

  // bias + deg*nv + LN + silu -> bf16 back into own wave's rows of Ahn
  #pragma unroll
  for (int r = 0; r < 4; ++r) {
    int row = n0 + w * 16 + lh * 4 + r;
    float degf = (row < n) ? (float)deg[row] : 0.f;
    float vals[8];
    #pragma unroll
    for (int nt = 0; nt < 8; ++nt) vals[nt] = acc[nt][r] + vb[nt] + degf * vn[nt];
    float s1 = 0.f, s2 = 0.f;
    #pragma unroll
    for (int nt = 0; nt < 8; ++nt) { s1 += vals[nt]; s2 += vals[nt] * vals[nt]; }
    #pragma unroll
    for (int m = 1; m < 16; m <<= 1) { s1 += __shfl_xor(s1, m, 64); s2 += __shfl_xor(s2, m, 64); }
    float mu = s1 * (1.0f / 128.0f);
    float var = s2 * (1.0f / 128.0f) - mu * mu;
    float rs = rsqrtf(var + 1e-5f);
    int lrow = w * 16 + lh * 4 + r;
    #pragma unroll
    for (int nt = 0; nt < 8; ++nt)
      Ahn[lrow][nt * 16 + lr] = f2bf(silu_f((vals[nt] - mu) * rs * gv[nt] + bv[nt]));
  }

  // GEMM2: @N2^T, residual + nb2
  f32x4 acc2[8];
  #pragma unroll
  for (int nt = 0; nt < 8; ++nt) acc2[nt] = zf;
  #pragma unroll
  for (int q = 0; q < 4; ++q) {
    short8 af = *(const short8*)&Ahn[w * 16 + lr][q * 32 + lh * 8];
    #pragma unroll
    for (int nt = 0; nt < 8; ++nt) {
      short8 bf = *(const short8*)(N2 + (size_t)(nt * 16 + lr) * HID + q * 32 + lh * 8);
      acc2[nt] = __builtin_amdgcn_mfma_f32_16x16x32_bf16(af, bf, acc2[nt], 0, 0, 0);
    }
  }

  float vb2[8];
  #pragma unroll
  for (int nt = 0; nt < 8; ++nt) vb2[nt] = nb2[nt * 16 + lr];
  #pragma unroll
  for (int r = 0; r < 4; ++r) {
    int row = n0 + w * 16 + lh * 4 + r;
    if (row < n) {
      const float* hr = Hn + (size_t)row * HID;
      float* cr = C + (size_t)row * HID;
      #pragma unroll
      for (int nt = 0; nt < 8; ++nt) {
        int col = nt * 16 + lr;
        cr[col] = hr[col] + acc2[nt][r] + vb2[nt];
      }
    }
  }
}

extern "C" void kernel_launch(void* const* d_in, const int* in_sizes, int n_in,
                              void* d_out, int out_size, void* d_ws, size_t ws_size,
                              hipStream_t stream)
{
  const float* in_h  = (const float*)d_in[0];
  const int*   edges = (const int*)d_in[1];
  const float* ea    = (const float*)d_in[2];
  const float* ei_w1 = (const float*)d_in[3];
  const float* ei_b1 = (const float*)d_in[4];
  const float* ei_w2 = (const float*)d_in[5];
  const float* ei_b2 = (const float*)d_in[6];
  const float* ng    = (const float*)d_in[7];
  const float* nbp   = (const float*)d_in[8];
  const float* ew1   = (const float*)d_in[9];
  const float* eb1   = (const float*)d_in[10];
  const float* elg   = (const float*)d_in[11];
  const float* elb   = (const float*)d_in[12];
  const float* ew2   = (const float*)d_in[13];
  const float* eb2   = (const float*)d_in[14];
  const float* nw1   = (const float*)d_in[15];
  const float* nb1   = (const float*)d_in[16];
  const float* nlg   = (const float*)d_in[17];
  const float* nlb   = (const float*)d_in[18];
  const float* nw2   = (const float*)d_in[19];
  const float* nb2   = (const float*)d_in[20];
  const float* eo_w1 = (const float*)d_in[21];
  const float* eo_b1 = (const float*)d_in[22];
  const float* eo_w2 = (const float*)d_in[23];
  const float* eo_b2 = (const float*)d_in[24];

  float* wf    = (float*)d_ws;
  float* B_h   = wf;
  float* B_hn  = wf + NNH;
  float* B_S   = wf + 2 * NNH;   // S (edge-sum); perm alias during setup
  float* B_tmp = wf + 3 * NNH;   // Pa
  float* B_pb  = wf + 4 * NNH;   // Pb

  const size_t WOFF = 5 * NNH;
  ushort* wu = (ushort*)(wf + WOFF);
  // ei1@0, ei2@16384, eo1@32768, eo2@49152; per-layer base 65536 + l*104448:
  //   Wab@0 [256][128] | W2N@32768 | N1a@49152 | N2@81920
  const size_t SOFF = WOFF + 262144;
  int* dst_s = (int*)(wf + SOFF);
  int* cnt   = dst_s + NE;       // = deg
  int* cur   = cnt + NPAD;
  int* base  = cur + NPAD;
  ushort* ea_s = (ushort*)(base + NPAD);
  float* nvb = (float*)(ea_s + (size_t)NE * 16);   // 4*128 fp32
  int* perm  = (int*)B_S;

  const int NB  = (NN + 63) / 64;
  const int NBE = (NN + 3) / 4;
  const int NEB = (NE + 255) / 256;

  const int* erow = edges;
  const int* ecol = edges + NE;

  // ---- counting sort by src (once) ----
  zero_i<<<(2 * NPAD + 255) / 256, 256, 0, stream>>>(cnt, 2 * NPAD);
  count_src<<<NEB, 256, 0, stream>>>(erow, cnt);
  scan_excl<<<1, 1024, 0, stream>>>(cnt, base, NN);
  place_edges<<<NEB, 256, 0, stream>>>(erow, ecol, base, cur, dst_s, perm);
  permute_ea_bf<<<(NE * 4 + 255) / 256, 256, 0, stream>>>((const float4*)ea, perm, ea_s);

  // ---- weight conversion / folding ----
  cvt4<<<256, 256, 0, stream>>>(ei_w1, ei_w2, eo_w1, eo_w2, wu);
  cvt_wab<<<512, 256, 0, stream>>>(ew1, wu + 65536);
  cvt_std<<<(4 * 16384 + 255) / 256, 256, 0, stream>>>(nw2, wu + 65536 + 81920, 128, 128, 16384);
  fold_w<<<512, 128, 0, stream>>>(nw1, ew2, eb2, wu + 65536, nvb);

  // ---- embedding_in (fused pair) ----
  emb2<<<NB, 256, 0, stream>>>(in_h, wu, ei_b1, wu + 16384, ei_b2, B_h, NN);

  for (int lyr = 0; lyr < 4; ++lyr) {
    ushort* lb = wu + 65536 + lyr * 104448;
    pab_ln<<<NB, 256, 0, stream>>>(B_h, lb, ng + 128 * lyr, nbp + 128 * lyr,
        eb1 + 128 * lyr, B_hn, B_tmp, B_pb, NN);
    node_edge<<<NBE, 256, 0, stream>>>(B_tmp, B_pb, ea_s, dst_s, base, cnt,
        ew1 + 34816 * lyr, elg + 128 * lyr, elb + 128 * lyr, B_S, NN);
    node_mlp<<<NB, 256, 0, stream>>>(B_hn, B_S, lb + 49152, lb + 32768, lb + 81920,
        nb1 + 128 * lyr, nvb + 128 * lyr, cnt,
        nlg + 128 * lyr, nlb + 128 * lyr, nb2 + 128 * lyr, B_h, NN);
  }

  // ---- embedding_out (fused pair) ----
  emb2<<<NB, 256, 0, stream>>>(B_h, wu + 32768, eo_b1, wu + 49152, eo_b2, (float*)d_out, NN);
}